// Round 17
// baseline (780.221 us; speedup 1.0000x reference)
//
#include <hip/hip_runtime.h>
#include <cstdint>
#include <cstddef>

#define D_MODEL   768
#define D_STATE   64
#define D_INNER   1536
#define HEADDIM   64
#define NHEADS    24
#define D_CONV    4
#define CONV_DIM  1664      // D_INNER + 2*D_STATE
#define D_IN_PROJ 3224      // 2*D_INNER + 2*D_STATE + NHEADS
#define BATCH     4
#define SEQLEN    2048
#define NROWS     (BATCH*SEQLEN)   // 8192
#define NCHUNK    32
#define Q         64               // chunk length

typedef unsigned short u16;
typedef __attribute__((ext_vector_type(8))) short bf16x8;
typedef __attribute__((ext_vector_type(8))) unsigned short u16x8;
typedef __attribute__((ext_vector_type(4))) float f32x4;

__device__ __forceinline__ int flip_row(int m, const int* __restrict__ lengths) {
    int b = m >> 11;
    int t = m & (SEQLEN - 1);
    int len = lengths[b];
    int ft = (t < len) ? (len - 1 - t) : t;
    return (b << 11) | ft;
}

__device__ __forceinline__ u16 f2bf(float f) {
    unsigned int u = __float_as_uint(f);
    unsigned int r = u + 0x7FFFu + ((u >> 16) & 1u);
    return (u16)(r >> 16);
}
__device__ __forceinline__ float bf2f(u16 h) {
    return __uint_as_float(((unsigned int)h) << 16);
}

// f32 -> (hi, lo) bf16 pair arrays
__global__ __launch_bounds__(256)
void convert_pair_kernel(const float* __restrict__ in, u16* __restrict__ hi,
                         u16* __restrict__ lo, int n4)
{
    int i = blockIdx.x * 256 + threadIdx.x;
    if (i >= n4) return;
    float4 v = *(const float4*)(in + (size_t)i * 4);
    ushort4 h, l;
    h.x = f2bf(v.x); l.x = f2bf(v.x - bf2f(h.x));
    h.y = f2bf(v.y); l.y = f2bf(v.y - bf2f(h.y));
    h.z = f2bf(v.z); l.z = f2bf(v.z - bf2f(h.z));
    h.w = f2bf(v.w); l.w = f2bf(v.w - bf2f(h.w));
    *(ushort4*)(hi + (size_t)i * 4) = h;
    *(ushort4*)(lo + (size_t)i * 4) = l;
}

// f32 -> single bf16 array
__global__ __launch_bounds__(256)
void convert_single_kernel(const float* __restrict__ in, u16* __restrict__ hi, int n4)
{
    int i = blockIdx.x * 256 + threadIdx.x;
    if (i >= n4) return;
    float4 v = *(const float4*)(in + (size_t)i * 4);
    ushort4 h;
    h.x = f2bf(v.x); h.y = f2bf(v.y); h.z = f2bf(v.z); h.w = f2bf(v.w);
    *(ushort4*)(hi + (size_t)i * 4) = h;
}

// prep for fused output projection: (a) op_w (768x1536) -> pairs (A-side of wd),
// (b) transpose out_w (768x1536) -> owT[1536][768] single bf16 (W-side of wd)
#define NCONV_BLK 1152    // 768*1536/4/256
#define NT_BLK    288     // 24 x 12 transpose tiles
__global__ __launch_bounds__(256)
void prep_outw_kernel(const float* __restrict__ op_w, const float* __restrict__ ow,
                      u16* __restrict__ oph, u16* __restrict__ opl,
                      u16* __restrict__ owTh)
{
    const int bid = blockIdx.x;
    const int tid = threadIdx.x;
    if (bid < NCONV_BLK) {
        int i = bid * 256 + tid;
        float4 v = *(const float4*)(op_w + (size_t)i * 4);
        ushort4 h, l;
        h.x = f2bf(v.x); l.x = f2bf(v.x - bf2f(h.x));
        h.y = f2bf(v.y); l.y = f2bf(v.y - bf2f(h.y));
        h.z = f2bf(v.z); l.z = f2bf(v.z - bf2f(h.z));
        h.w = f2bf(v.w); l.w = f2bf(v.w - bf2f(h.w));
        *(ushort4*)(oph + (size_t)i * 4) = h;
        *(ushort4*)(opl + (size_t)i * 4) = l;
        return;
    }
    __shared__ float T[64][65];
    const int tb = bid - NCONV_BLK;
    const int e0 = (tb % 24) * 64;
    const int d0 = (tb / 24) * 64;
    const int col = tid & 63, rg = tid >> 6;
    #pragma unroll
    for (int i = 0; i < 16; i++) {
        int r = rg + i * 4;
        T[r][col] = ow[(size_t)(d0 + r) * D_INNER + e0 + col];
    }
    __syncthreads();
    const int er = tid >> 2, dc0 = (tid & 3) * 16;
    u16x8 ph[2];
    #pragma unroll
    for (int j = 0; j < 16; j++)
        ph[j >> 3][j & 7] = f2bf(T[dc0 + j][er]);
    size_t obase = (size_t)(e0 + er) * D_MODEL + d0 + dc0;
    *(u16x8*)(owTh + obase)     = ph[0];
    *(u16x8*)(owTh + obase + 8) = ph[1];
}

// ---------- 2-term split-bf16 MFMA GEMM, BK=64, reg-staged 1-deep prefetch ----------
// (R14 version: measured best at 114 us in_proj; dbuf variant falsified in R16)
// 128x128 tile, 256 threads = 4 waves (2x2), 4x4 16x16 frags/wave.
// LDS 48 KB (3 matrices x 16 KB) -> 3 blocks/CU.
// mode 0: C f32 = scale*acc + bias[n] + resid[m]
// mode 1: split store -> Cz | Cxbc
// mode 3: C[crow*ldc+n] += scale*acc
// mode 4: Cp[crow*ldc+n] = bf16(acc)
__global__ __launch_bounds__(256, 3)
void mfma_gemm(const u16* __restrict__ Ahi, const u16* __restrict__ Alo, int lda,
               const u16* __restrict__ W, int ldw,
               int N, int K, const int* __restrict__ lengths,
               int flipA, int flipC, int mode,
               float* __restrict__ C, int ldc,
               float* __restrict__ Cz, float* __restrict__ Cxbc,
               u16* __restrict__ Cp,
               const float* __restrict__ bias, const float* __restrict__ resid,
               const float* __restrict__ sqsum)
{
    __shared__ alignas(16) u16 lds[3 * 8192];
    const int tid = threadIdx.x;
    const int m0 = blockIdx.y * 128;
    const int n0 = blockIdx.x * 128;
    const int lane = tid & 63;
    const int wid = tid >> 6;
    const int wm = wid >> 1, wn = wid & 1;

    const int kh = tid & 7;           // k-group (8 u16 each), 0..7
    const int rb = tid >> 3;          // 0..31
    int aoff[4], woff[4], lws[4];
    #pragma unroll
    for (int c = 0; c < 4; c++) {
        int row = rb + c * 32;
        int grow = m0 + row;
        if (flipA) grow = flip_row(grow, lengths);
        aoff[c] = grow * lda + kh * 8;
        int wrow = n0 + row; if (wrow >= N) wrow = N - 1;
        woff[c] = wrow * ldw + kh * 8;
        lws[c] = kh * 1024 + ((row & 0x78) | ((row ^ kh) & 7)) * 8;
    }

    f32x4 acc[4][4];
    const f32x4 zero4 = {0.f, 0.f, 0.f, 0.f};
    #pragma unroll
    for (int i = 0; i < 4; i++)
        #pragma unroll
        for (int j = 0; j < 4; j++) acc[i][j] = zero4;

    const int l15 = lane & 15, lq = lane >> 4;
    const int arow0 = wm * 64 + l15;
    const int wrow0 = wn * 64 + l15;

    // prologue: load tile 0 into registers
    u16x8 va[4], vb[4], vc[4];
    #pragma unroll
    for (int c = 0; c < 4; c++) {
        va[c] = *(const u16x8*)(Ahi + (size_t)aoff[c]);
        vb[c] = *(const u16x8*)(Alo + (size_t)aoff[c]);
        vc[c] = *(const u16x8*)(W   + (size_t)woff[c]);
    }

    for (int kt = 0; kt < K; kt += 64) {
        __syncthreads();                       // all waves done reading LDS
        #pragma unroll
        for (int c = 0; c < 4; c++) {
            *(u16x8*)(lds + 0 * 8192 + lws[c]) = va[c];
            *(u16x8*)(lds + 1 * 8192 + lws[c]) = vb[c];
            *(u16x8*)(lds + 2 * 8192 + lws[c]) = vc[c];
        }
        __syncthreads();                       // tile staged
        if (kt + 64 < K) {                     // prefetch next tile
            #pragma unroll
            for (int c = 0; c < 4; c++) {
                va[c] = *(const u16x8*)(Ahi + (size_t)aoff[c] + kt + 64);
                vb[c] = *(const u16x8*)(Alo + (size_t)aoff[c] + kt + 64);
                vc[c] = *(const u16x8*)(W   + (size_t)woff[c] + kt + 64);
            }
        }
        #pragma unroll
        for (int kk = 0; kk < 2; kk++) {
            const int khs = kk * 4 + lq;
            const int abase = khs * 1024 + ((arow0 & 0x78) | ((arow0 ^ khs) & 7)) * 8;
            const int wbase = khs * 1024 + ((wrow0 & 0x78) | ((wrow0 ^ khs) & 7)) * 8;
            bf16x8 ah[4], al[4], wv[4];
            #pragma unroll
            for (int f = 0; f < 4; f++) {
                ah[f] = *(const bf16x8*)(lds + 0 * 8192 + abase + f * 128);
                al[f] = *(const bf16x8*)(lds + 1 * 8192 + abase + f * 128);
                wv[f] = *(const bf16x8*)(lds + 2 * 8192 + wbase + f * 128);
            }
            #pragma unroll
            for (int fr = 0; fr < 4; fr++)
                #pragma unroll
                for (int fc = 0; fc < 4; fc++) {
                    acc[fr][fc] = __builtin_amdgcn_mfma_f32_16x16x32_bf16(
                        ah[fr], wv[fc], acc[fr][fc], 0, 0, 0);
                    acc[fr][fc] = __builtin_amdgcn_mfma_f32_16x16x32_bf16(
                        al[fr], wv[fc], acc[fr][fc], 0, 0, 0);
                }
        }
    }

    #pragma unroll
    for (int fr = 0; fr < 4; fr++) {
        int mr[4], crow[4];
        float scl[4];
        #pragma unroll
        for (int r = 0; r < 4; r++) {
            mr[r] = m0 + wm * 64 + fr * 16 + lq * 4 + r;
            crow[r] = flipC ? flip_row(mr[r], lengths) : mr[r];
            scl[r] = sqsum ? rsqrtf(sqsum[mr[r]] * (1.f / D_INNER) + 1e-5f) : 1.f;
        }
        #pragma unroll
        for (int fc = 0; fc < 4; fc++) {
            const int nb = n0 + wn * 64 + fc * 16;
            const int nn = nb + l15;
            if (nn >= N) continue;
            #pragma unroll
            for (int r = 0; r < 4; r++) {
                float v = acc[fr][fc][r];
                if (mode == 1) {
                    if (nb < D_INNER)
                        Cz[(size_t)crow[r] * D_INNER + nn] = v;
                    else if (nb < D_INNER + CONV_DIM)
                        Cxbc[(size_t)crow[r] * CONV_DIM + (nn - D_INNER)] = v;
                } else if (mode == 3) {
                    C[(size_t)crow[r] * ldc + nn] += v * scl[r];
                } else if (mode == 4) {
                    Cp[(size_t)crow[r] * ldc + nn] = f2bf(v);
                } else {
                    v = v * scl[r] + bias[nn] + resid[(size_t)mr[r] * D_MODEL + nn];
                    C[(size_t)crow[r] * ldc + nn] = v;
                }
            }
        }
    }
}

// ---------- WIDE 2-term GEMM for in_proj: 128x256 tile, BK=32 ----------
// 256 threads = 4 waves (2x2), wave tile 64x128 -> acc[4][8] (128 VGPR).
// LDS 32 KB single-buffer (A hi 8K | A lo 8K | W 16K).
// A-fragment reused 8x, W 4x -> 4 B LDS-read per MFMA (was 6).
// Same k-accumulation order as mfma_gemm -> bit-identical output.
// Split store: n < 1536 -> Cz ; 1536 <= n < 3200 -> Cxbc ; n >= 3200 skipped.
__global__ __launch_bounds__(256, 2)
void mfma_gemm_wide(const u16* __restrict__ Ahi, const u16* __restrict__ Alo, int lda,
                    const u16* __restrict__ W, int ldw,
                    int N, int K, const int* __restrict__ lengths, int flipA,
                    float* __restrict__ Cz, float* __restrict__ Cxbc)
{
    __shared__ alignas(16) u16 lds[16384];   // Ahi[4096] Alo[4096] W[8192]
    const int tid = threadIdx.x;
    const int m0 = blockIdx.y * 128;
    const int n0 = blockIdx.x * 256;
    const int lane = tid & 63;
    const int wid = tid >> 6;
    const int wm = wid >> 1, wn = wid & 1;

    const int kh = tid & 3;           // k-group (8 u16 each), 0..3
    const int rb = tid >> 2;          // 0..63
    int aoff[2], lwsA[2];
    #pragma unroll
    for (int c = 0; c < 2; c++) {
        int row = rb + c * 64;
        int grow = m0 + row;
        if (flipA) grow = flip_row(grow, lengths);
        aoff[c] = grow * lda + kh * 8;
        lwsA[c] = kh * 1024 + ((row & 0x78) | ((row ^ (kh << 1)) & 7)) * 8;
    }
    int woff[4], lwsW[4];
    #pragma unroll
    for (int c = 0; c < 4; c++) {
        int row = rb + c * 64;        // 0..255
        int wrow = n0 + row; if (wrow >= N) wrow = N - 1;
        woff[c] = wrow * ldw + kh * 8;
        lwsW[c] = kh * 2048 + ((row & 0xF8) | ((row ^ (kh << 1)) & 7)) * 8;
    }

    f32x4 acc[4][8];
    const f32x4 zero4 = {0.f, 0.f, 0.f, 0.f};
    #pragma unroll
    for (int i = 0; i < 4; i++)
        #pragma unroll
        for (int j = 0; j < 8; j++) acc[i][j] = zero4;

    const int l15 = lane & 15, lq = lane >> 4;
    const int arow0 = wm * 64 + l15;
    const int wrow0 = wn * 128 + l15;
    const int abase = lq * 1024 + ((arow0 & 0x78) | ((arow0 ^ (lq << 1)) & 7)) * 8;
    const int wbase = lq * 2048 + ((wrow0 & 0xF8) | ((wrow0 ^ (lq << 1)) & 7)) * 8;

    // prologue: load tile 0 into registers
    u16x8 va[2], vb[2], vc[4];
    #pragma unroll
    for (int c = 0; c < 2; c++) {
        va[c] = *(const u16x8*)(Ahi + (size_t)aoff[c]);
        vb[c] = *(const u16x8*)(Alo + (size_t)aoff[c]);
    }
    #pragma unroll
    for (int c = 0; c < 4; c++)
        vc[c] = *(const u16x8*)(W + (size_t)woff[c]);

    for (int kt = 0; kt < K; kt += 32) {
        __syncthreads();                       // all waves done reading LDS
        #pragma unroll
        for (int c = 0; c < 2; c++) {
            *(u16x8*)(lds + lwsA[c])        = va[c];
            *(u16x8*)(lds + 4096 + lwsA[c]) = vb[c];
        }
        #pragma unroll
        for (int c = 0; c < 4; c++)
            *(u16x8*)(lds + 8192 + lwsW[c]) = vc[c];
        __syncthreads();                       // tile staged
        if (kt + 32 < K) {                     // prefetch next tile
            #pragma unroll
            for (int c = 0; c < 2; c++) {
                va[c] = *(const u16x8*)(Ahi + (size_t)aoff[c] + kt + 32);
                vb[c] = *(const u16x8*)(Alo + (size_t)aoff[c] + kt + 32);
            }
            #pragma unroll
            for (int c = 0; c < 4; c++)
                vc[c] = *(const u16x8*)(W + (size_t)woff[c] + kt + 32);
        }
        bf16x8 ah[4], al[4], wv[8];
        #pragma unroll
        for (int f = 0; f < 4; f++) {
            ah[f] = *(const bf16x8*)(lds + abase + f * 128);
            al[f] = *(const bf16x8*)(lds + 4096 + abase + f * 128);
        }
        #pragma unroll
        for (int f = 0; f < 8; f++)
            wv[f] = *(const bf16x8*)(lds + 8192 + wbase + f * 128);
        #pragma unroll
        for (int fr = 0; fr < 4; fr++)
            #pragma unroll
            for (int fc = 0; fc < 8; fc++) {
                acc[fr][fc] = __builtin_amdgcn_mfma_f32_16x16x32_bf16(
                    ah[fr], wv[fc], acc[fr][fc], 0, 0, 0);
                acc[fr][fc] = __builtin_amdgcn_mfma_f32_16x16x32_bf16(
                    al[fr], wv[fc], acc[fr][fc], 0, 0, 0);
            }
    }

    #pragma unroll
    for (int fr = 0; fr < 4; fr++) {
        int crow[4];
        #pragma unroll
        for (int r = 0; r < 4; r++)
            crow[r] = m0 + wm * 64 + fr * 16 + lq * 4 + r;
        #pragma unroll
        for (int fc = 0; fc < 8; fc++) {
            const int nb = n0 + wn * 128 + fc * 16;
            const int nn = nb + l15;
            if (nn >= N) continue;
            #pragma unroll
            for (int r = 0; r < 4; r++) {
                float v = acc[fr][fc][r];
                if (nb < D_INNER)
                    Cz[(size_t)crow[r] * D_INNER + nn] = v;
                else if (nb < D_INNER + CONV_DIM)
                    Cxbc[(size_t)crow[r] * CONV_DIM + (nn - D_INNER)] = v;
                // dt columns handled exactly by dt_exact_kernel
            }
        }
    }
}

// exact fp32 dt_raw: la[row][h] = dot(x[fliprow], in_w[3200+h])  (24 heads)
__global__ __launch_bounds__(256)
void dt_exact_kernel(const float* __restrict__ x, const float* __restrict__ wdt,
                     const int* __restrict__ lengths, int flipA,
                     float* __restrict__ la)
{
    const int wv = threadIdx.x >> 6, lane = threadIdx.x & 63;
    const int row = blockIdx.x * 4 + wv;
    int grow = flipA ? flip_row(row, lengths) : row;
    const float* xr = x + (size_t)grow * D_MODEL;
    float xv[12];
    #pragma unroll
    for (int k = 0; k < 12; k++) xv[k] = xr[k * 64 + lane];
    for (int c = 0; c < NHEADS; c++) {
        const float* wr = wdt + (size_t)c * D_MODEL;
        float acc = 0.f;
        #pragma unroll
        for (int k = 0; k < 12; k++) acc = fmaf(xv[k], wr[k * 64 + lane], acc);
        #pragma unroll
        for (int o = 32; o > 0; o >>= 1) acc += __shfl_xor(acc, o);
        if (lane == 0) la[(size_t)row * NHEADS + c] = acc;
    }
}

// fused causal conv + silu + per-chunk transpose + (cg==26) dt/cumsum
__global__ __launch_bounds__(256)
void conv_silu_fused_kernel(const float* __restrict__ xbcr, const float* __restrict__ cw,
                            const float* __restrict__ cb,
                            u16* __restrict__ xTh, u16* __restrict__ xTl,
                            u16* __restrict__ bch, u16* __restrict__ bcl,
                            const float* __restrict__ dt_bias, const float* __restrict__ A_log,
                            float* __restrict__ dtb, float* __restrict__ la)
{
    __shared__ float T[64][65];
    const int cg = blockIdx.x;
    const int rc = blockIdx.y;
    const int tid = threadIdx.x;
    if (cg == 26) {
        const int lane2 = tid & 63, w = tid >> 6;
        const int row0 = rc * 64;
        #pragma unroll
        for (int i = 0; i < 6; i++) {
            int h = w * 6 + i;
            size_t idx = (size_t)(row0 + lane2) * NHEADS + h;
            float v = la[idx] + dt_bias[h];
            float sp = (v > 20.f) ? v : log1pf(expf(v));
            dtb[idx] = sp;
            float dA = sp * (-expf(A_log[h]));
            #pragma unroll
            for (int o = 1; o < 64; o <<= 1) {
                float u = __shfl_up(dA, o);
                if (lane2 >= o) dA += u;
            }
            la[idx] = dA;
        }
        return;
    }
    const int col = tid & 63, rg = tid >> 6;
    const int c = cg * 64 + col;
    const int rstart = rc * 64 + rg * 16;
    const int t0 = rstart & (SEQLEN - 1);
    const float c0 = cw[c*4+0], c1 = cw[c*4+1], c2 = cw[c*4+2], c3 = cw[c*4+3];
    const float cbv = cb[c];
    const float* base = xbcr + (size_t)rstart * CONV_DIM + c;
    float w0 = (t0 >= 3) ? base[-3 * CONV_DIM] : 0.f;
    float w1 = (t0 >= 2) ? base[-2 * CONV_DIM] : 0.f;
    float w2 = (t0 >= 1) ? base[-1 * CONV_DIM] : 0.f;
    const bool isx = (cg < 24);
    #pragma unroll
    for (int r = 0; r < 16; r++) {
        float w3 = base[r * CONV_DIM];
        float acc = cbv + w0*c0 + w1*c1 + w2*c2 + w3*c3;
        float val = acc / (1.f + expf(-acc));
        if (isx) {
            T[rg*16 + r][col] = val;
        } else {
            size_t gi = (size_t)(rstart + r) * 128 + (c - D_INNER);
            u16 hh = f2bf(val);
            bch[gi] = hh;
            bcl[gi] = f2bf(val - bf2f(hh));
        }
        w0 = w1; w1 = w2; w2 = w3;
    }
    if (!isx) return;
    __syncthreads();
    const int p = tid >> 2, s0 = (tid & 3) * 16;
    size_t tile = (size_t)(((rc >> 5) * NHEADS + cg) * NCHUNK + (rc & 31));
    size_t obase = tile * 4096 + p * 64 + s0;
    u16x8 ph[2], pl[2];
    #pragma unroll
    for (int j = 0; j < 16; j++) {
        float v = T[s0 + j][p];
        u16 hh = f2bf(v);
        ph[j >> 3][j & 7] = hh;
        pl[j >> 3][j & 7] = f2bf(v - bf2f(hh));
    }
    *(u16x8*)(xTh + obase)     = ph[0];
    *(u16x8*)(xTh + obase + 8) = ph[1];
    *(u16x8*)(xTl + obase)     = pl[0];
    *(u16x8*)(xTl + obase + 8) = pl[1];
}

// 3-term split-bf16 64x64x64 GEMM helper on staged LDS regions
__device__ __forceinline__ void gemm3(const u16* rA, const u16* rW,
                                      int ar0, int wr0, int lq, f32x4 acc[2][2])
{
    #pragma unroll
    for (int kk = 0; kk < 2; kk++) {
        const int khs = kk * 4 + lq;
        const int ab = khs * 512 + ((ar0 & 0x38) | ((ar0 ^ khs) & 7)) * 8;
        const int wb = khs * 512 + ((wr0 & 0x38) | ((wr0 ^ khs) & 7)) * 8;
        bf16x8 ah[2], al[2], wh[2], wl[2];
        #pragma unroll
        for (int f = 0; f < 2; f++) {
            ah[f] = *(const bf16x8*)(rA + ab + f * 128);
            al[f] = *(const bf16x8*)(rA + 4096 + ab + f * 128);
            wh[f] = *(const bf16x8*)(rW + wb + f * 128);
            wl[f] = *(const bf16x8*)(rW + 4096 + wb + f * 128);
        }
        #pragma unroll
        for (int fr = 0; fr < 2; fr++)
            #pragma unroll
            for (int fc = 0; fc < 2; fc++) {
                acc[fr][fc] = __builtin_amdgcn_mfma_f32_16x16x32_bf16(ah[fr], wh[fc], acc[fr][fc], 0, 0, 0);
                acc[fr][fc] = __builtin_amdgcn_mfma_f32_16x16x32_bf16(ah[fr], wl[fc], acc[fr][fc], 0, 0, 0);
                acc[fr][fc] = __builtin_amdgcn_mfma_f32_16x16x32_bf16(al[fr], wh[fc], acc[fr][fc], 0, 0, 0);
            }
    }
}

// chunk state: S(p,n) = sum_s exp(la63-la[s]) dt[s] x[s][p] B[s][n]  -> hloc[tile]
__global__ __launch_bounds__(256)
void chunk_state_kernel(const u16* __restrict__ xTh, const u16* __restrict__ xTl,
                        const u16* __restrict__ bch, const u16* __restrict__ bcl,
                        const float* __restrict__ la, const float* __restrict__ dtb,
                        float* __restrict__ hloc)
{
    __shared__ alignas(16) u16 lA[2 * 4096];
    __shared__ alignas(16) u16 lW[2 * 4096];
    __shared__ float la_sh[64], w_sh[64];
    const int bh = blockIdx.x, c = blockIdx.y;
    const int b = bh / NHEADS, h = bh - b * NHEADS;
    const int row0 = b * SEQLEN + c * Q;
    const size_t tile = (size_t)(bh * NCHUNK + c);
    const int tid = threadIdx.x;

    if (tid < 64) la_sh[tid] = la[(size_t)(row0 + tid) * NHEADS + h];
    __syncthreads();
    if (tid < 64)
        w_sh[tid] = expf(la_sh[63] - la_sh[tid]) * dtb[(size_t)(row0 + tid) * NHEADS + h];
    {
        const int kh = tid & 7, rr = tid >> 3;
        #pragma unroll
        for (int cc = 0; cc < 2; cc++) {
            int row = rr + cc * 32;
            int lws = kh * 512 + ((row & 0x38) | ((row ^ kh) & 7)) * 8;
            *(u16x8*)(lA + lws)        = *(const u16x8*)(xTh + tile * 4096 + row * 64 + kh * 8);
            *(u16x8*)(lA + 4096 + lws) = *(const u16x8*)(xTl + tile * 4096 + row * 64 + kh * 8);
        }
    }
    __syncthreads();
    {
        const int n = tid & 63, sg = tid >> 6;
        #pragma unroll
        for (int i = 0; i < 16; i++) {
            int s = sg + i * 4;
            size_t gidx = (size_t)(row0 + s) * 128 + n;
            float bv = bf2f(bch[gidx]) + bf2f(bcl[gidx]);
            float v = bv * w_sh[s];
            u16 hh = f2bf(v), ll = f2bf(v - bf2f(hh));
            int addr = (s >> 3) * 512 + ((n & 0x38) | ((n ^ (s >> 3)) & 7)) * 8 + (s & 7);
            lW[addr] = hh;
            lW[4096 + addr] = ll;
        }
    }
    __syncthreads();
    const int lane = tid & 63, wid = tid >> 6;
    const int wm = wid >> 1, wn = wid & 1;
    const int l15 = lane & 15, lq = lane >> 4;
    f32x4 acc[2][2];
    const f32x4 z4 = {0.f, 0.f, 0.f, 0.f};
    acc[0][0] = z4; acc[0][1] = z4; acc[1][0] = z4; acc[1][1] = z4;
    gemm3(lA, lW, wm * 32 + l15, wn * 32 + l15, lq, acc);
    #pragma unroll
    for (int fr = 0; fr < 2; fr++)
        #pragma unroll
        for (int fc = 0; fc < 2; fc++)
            #pragma unroll
            for (int r = 0; r < 4; r++) {
                int p = wm * 32 + fr * 16 + lq * 4 + r;
                int n = wn * 32 + fc * 16 + l15;
                hloc[tile * 4096 + p * 64 + n] = acc[fr][fc][r];
            }
}

// in-place sequential fold: hloc[c] := state ENTERING chunk c
// grid (96 bh, 16 p-slices) x 256 threads
__global__ __launch_bounds__(256)
void combine_kernel(float* __restrict__ hloc, const float* __restrict__ la)
{
    const int bh = blockIdx.x;
    const int b = bh / NHEADS, h = bh - b * NHEADS;
    const int off = blockIdx.y * 256 + threadIdx.x;
    float run = 0.f;
    for (int c = 0; c < NCHUNK; c++) {
        float* ptr = hloc + ((size_t)(bh * NCHUNK + c)) * 4096 + off;
        float sv = *ptr;
        *ptr = run;
        float cd = expf(la[(size_t)(b * SEQLEN + c * Q + Q - 1) * NHEADS + h]);
        run = fmaf(run, cd, sv);
    }
}

// chunk y + fused gate/norm_w/sqsum
__global__ __launch_bounds__(256)
void chunk_y_kernel(const u16* __restrict__ xTh, const u16* __restrict__ xTl,
                    const u16* __restrict__ bch, const u16* __restrict__ bcl,
                    const float* __restrict__ hloc, const float* __restrict__ la,
                    const float* __restrict__ dtb, const float* __restrict__ Dp,
                    const float* __restrict__ z, const float* __restrict__ norm_w,
                    u16* __restrict__ ygp, float* __restrict__ sqsum)
{
    __shared__ alignas(16) u16 r1[2 * 4096];
    __shared__ alignas(16) u16 r2[2 * 4096];
    __shared__ float la_sh[64], dt_sh[64], ssh[64];
    const int bh = blockIdx.x, c = blockIdx.y;
    const int b = bh / NHEADS, h = bh - b * NHEADS;
    const int row0 = b * SEQLEN + c * Q;
    const size_t tile = (size_t)(bh * NCHUNK + c);
    const int tid = threadIdx.x;
    if (tid < 64) {
        la_sh[tid] = la[(size_t)(row0 + tid) * NHEADS + h];
        dt_sh[tid] = dtb[(size_t)(row0 + tid) * NHEADS + h];
        ssh[tid] = 0.f;
    }
    const int kh = tid & 7, rr = tid >> 3;
    #pragma unroll
    for (int cc = 0; cc < 2; cc++) {
        int row = rr + cc * 32;
        int lws = kh * 512 + ((row & 0x38) | ((row ^ kh) & 7)) * 8;
        *(u16x8*)(r1 + lws)        = *(const u16x8*)(bch + (size_t)(row0 + row) * 128 + 64 + kh * 8);
        *(u16x8*)(r1 + 4096 + lws) = *(const u16x8*)(bcl + (size_t)(row0 + row) * 128 + 64 + kh * 8);
        float4 f0 = *(const float4*)(hloc + tile * 4096 + row * 64 + kh * 8);
        float4 f1 = *(const float4*)(hloc + tile * 4096 + row * 64 + kh * 8 + 4);
        float vals[8] = {f0.x, f0.y, f0.z, f0.w, f1.x, f1.y, f1.z, f1.w};
        u16x8 hh, ll;
        #pragma unroll
        for (int j = 0; j < 8; j++) {
            u16 a = f2bf(vals[j]);
            hh[j] = a;
            ll[j] = f2bf(vals[j] - bf2f(a));
        }
        *(u16x8*)(r2 + lws) = hh;
        *(u16x8*)(r2 + 4096 + lws) = ll;
    }
    __syncthreads();
    const int lane = tid & 63, wid = tid >> 6;
    const int wm = wid >> 1, wn = wid & 1;
    const int l15 = lane & 15, lq = lane >> 4;
    const int ar0 = wm * 32 + l15, wr0 = wn * 32 + l15;
    const f32x4 z4 = {0.f, 0.f, 0.f, 0.f};
    f32x4 acc2[2][2];
    acc2[0][0] = z4; acc2[0][1] = z4; acc2[1][0] = z4; acc2[1][1] = z4;
    gemm3(r1, r2, ar0, wr0, lq, acc2);
    __syncthreads();
    #pragma unroll
    for (int cc = 0; cc < 2; cc++) {
        int row = rr + cc * 32;
        int lws = kh * 512 + ((row & 0x38) | ((row ^ kh) & 7)) * 8;
        *(u16x8*)(r2 + lws)        = *(const u16x8*)(bch + (size_t)(row0 + row) * 128 + kh * 8);
        *(u16x8*)(r2 + 4096 + lws) = *(const u16x8*)(bcl + (size_t)(row0 + row) * 128 + kh * 8);
    }
    __syncthreads();
    f32x4 accG[2][2];
    accG[0][0] = z4; accG[0][1] = z4; accG[1][0] = z4; accG[1][1] = z4;
    gemm3(r1, r2, ar0, wr0, lq, accG);
    __syncthreads();
    const float Dph = Dp[h];
    #pragma unroll
    for (int fr = 0; fr < 2; fr++)
        #pragma unroll
        for (int fc = 0; fc < 2; fc++)
            #pragma unroll
            for (int r = 0; r < 4; r++) {
                int t = wm * 32 + fr * 16 + lq * 4 + r;
                int s = wn * 32 + fc * 16 + l15;
                float v = 0.f;
                if (s <= t) v = accG[fr][fc][r] * expf(la_sh[t] - la_sh[s]) * dt_sh[s];
                if (s == t) v += Dph;
                u16 hh = f2bf(v), ll = f2bf(v - bf2f(hh));
                int addr = (s >> 3) * 512 + ((t & 0x38) | ((t ^ (s >> 3)) & 7)) * 8 + (s & 7);
                r1[addr] = hh;
                r1[4096 + addr] = ll;
            }
    #pragma unroll
    for (int cc = 0; cc < 2; cc++) {
        int row = rr + cc * 32;
        int lws = kh * 512 + ((row & 0x38) | ((row ^ kh) & 7)) * 8;
        *(u16x8*)(r2 + lws)        = *(const u16x8*)(xTh + tile * 4096 + row * 64 + kh * 8);
        *(u16x8*)(r2 + 4096 + lws) = *(const u16x8*)(xTl + tile * 4096 + row * 64 + kh * 8);
    }
    __syncthreads();
    f32x4 acc1[2][2];
    acc1[0][0] = z4; acc1[0][1] = z4; acc1[1][0] = z4; acc1[1][1] = z4;
    gemm3(r1, r2, ar0, wr0, lq, acc1);
    // fused epilogue: gate + norm_w + pair store + sqsum
    #pragma unroll
    for (int fr = 0; fr < 2; fr++)
        #pragma unroll
        for (int r = 0; r < 4; r++) {
            int t = wm * 32 + fr * 16 + lq * 4 + r;
            size_t row = row0 + t;
            float Et = expf(la_sh[t]);
            float s2 = 0.f;
            #pragma unroll
            for (int fc = 0; fc < 2; fc++) {
                int hp = h * 64 + wn * 32 + fc * 16 + l15;
                float yv = acc1[fr][fc][r] + Et * acc2[fr][fc][r];
                float zv = z[row * D_INNER + hp];
                float gv = yv * (zv / (1.f + expf(-zv)));
                s2 = fmaf(gv, gv, s2);
                float gn = gv * norm_w[hp];
                u16 hh = f2bf(gn);
                ygp[row * 3072 + hp] = hh;
                ygp[row * 3072 + 1536 + hp] = f2bf(gn - bf2f(hh));
            }
            s2 += __shfl_xor(s2, 1);
            s2 += __shfl_xor(s2, 2);
            s2 += __shfl_xor(s2, 4);
            s2 += __shfl_xor(s2, 8);
            if (l15 == 0) atomicAdd(&ssh[t], s2);
        }
    __syncthreads();
    if (tid < 64) atomicAdd(&sqsum[row0 + tid], ssh[tid]);
}

__global__ __launch_bounds__(256)
void layernorm_kernel(const float* __restrict__ r, const float* __restrict__ gam,
                      const float* __restrict__ bet, float* __restrict__ out)
{
    const int row = blockIdx.x;
    const float* rr = r + (size_t)row * D_MODEL;
    const int tid = threadIdx.x;
    float v[3];
    float s = 0.f, s2 = 0.f;
    #pragma unroll
    for (int i = 0; i < 3; i++) {
        v[i] = rr[tid + i * 256];
        s += v[i];
        s2 = fmaf(v[i], v[i], s2);
    }
    #pragma unroll
    for (int o = 32; o > 0; o >>= 1) { s += __shfl_xor(s, o); s2 += __shfl_xor(s2, o); }
    __shared__ float rs[4], rs2[4];
    if ((tid & 63) == 0) { rs[tid >> 6] = s; rs2[tid >> 6] = s2; }
    __syncthreads();
    float S  = rs[0] + rs[1] + rs[2] + rs[3];
    float S2 = rs2[0] + rs2[1] + rs2[2] + rs2[3];
    float mu  = S * (1.f / D_MODEL);
    float var = S2 * (1.f / D_MODEL) - mu * mu;
    float inv = rsqrtf(var + 1e-5f);
    #pragma unroll
    for (int i = 0; i < 3; i++) {
        int e = tid + i * 256;
        out[(size_t)row * D_MODEL + e] = (v[i] - mu) * inv * gam[e] + bet[e];
    }
}

extern "C" void kernel_launch(void* const* d_in, const int* in_sizes, int n_in,
                              void* d_out, int out_size, void* d_ws, size_t ws_size,
                              hipStream_t stream)
{
    const float* x        = (const float*)d_in[0];
    const int*   lengths  = (const int*)d_in[1];
    const float* in_w[2]    = {(const float*)d_in[2],  (const float*)d_in[10]};
    const float* conv_w[2]  = {(const float*)d_in[3],  (const float*)d_in[11]};
    const float* conv_b[2]  = {(const float*)d_in[4],  (const float*)d_in[12]};
    const float* dt_bias[2] = {(const float*)d_in[5],  (const float*)d_in[13]};
    const float* A_log[2]   = {(const float*)d_in[6],  (const float*)d_in[14]};
    const float* Dp[2]      = {(const float*)d_in[7],  (const float*)d_in[15]};
    const float* norm_w[2]  = {(const float*)d_in[8],  (const float*)d_in[16]};
    const float* out_w[2]   = {(const float*)d_in[9],  (const float*)d_in[17]};
    const float* op_w = (const float*)d_in[18];
    const float* op_b = (const float*)d_in[19];
    const float* ln_g = (const float*)d_in[20];
    const float* ln_b = (const float*)d_in[21];
    float* outp = (float*)d_out;

    // ---- workspace layout (same 262.4 MB footprint) ----
    float* z    = (float*)d_ws;                               // R0: 8192*1536
    float* xbcr = z + (size_t)NROWS * D_INNER;                // R1: 8192*1664 (-> hloc)
    float* la   = xbcr + (size_t)NROWS * CONV_DIM;            // R2a
    float* dtb  = la  + (size_t)NROWS * NHEADS;               // R2b
    float* sqs  = dtb + (size_t)NROWS * NHEADS;               // R2c: 8192 f32 (sqsum)
    u16*  xTh   = (u16*)(sqs + (size_t)NROWS * NHEADS);       // R3
    u16*  xTl   = xTh + (size_t)NROWS * D_INNER;
    u16*  bch   = xTl + (size_t)NROWS * D_INNER;
    u16*  bcl   = bch + (size_t)NROWS * 128;
    float* ybuf = (float*)(bcl + (size_t)NROWS * 128);        // R4
    u16*  R5    = (u16*)(ybuf + (size_t)NROWS * D_INNER);     // R5

    float* hloc  = xbcr;          // after conv, xbcr dead -> chunk states

    // R5: persistent x pairs + final residual
    u16*  xq_h = R5;
    u16*  xq_l = R5 + (size_t)NROWS * D_MODEL;
    float* rbuf = (float*)(R5 + 2 * (size_t)NROWS * D_MODEL);

    // per-dir transient: in_w single bf16 in R4 (dead until chunk_y)
    u16* iw   = (u16*)ybuf;
    u16* yg_p = (u16*)ybuf;

    // per-dir out-proj prep in R3 (dead after chunk_y)
    u16* oph  = xTh;
    u16* opl  = oph  + (size_t)D_MODEL * D_INNER;
    u16* owTh = opl  + (size_t)D_MODEL * D_INNER;
    u16* wdp  = owTh + (size_t)D_MODEL * D_INNER;   // 768 x 1536 single bf16

    size_t need = ((size_t)NROWS * (D_INNER + CONV_DIM + 3*NHEADS + CONV_DIM +
                                    D_INNER + D_INNER)) * sizeof(float);
    if (ws_size < need) return;

    // x pairs once (flip handled by GEMM row indexing)
    convert_pair_kernel<<<(NROWS*D_MODEL/4 + 255)/256, 256, 0, stream>>>(
        x, xq_h, xq_l, NROWS*D_MODEL/4);

    for (int dir = 0; dir < 2; dir++) {
        // 0. convert in_w single bf16 (R4)
        convert_single_kernel<<<(D_IN_PROJ*D_MODEL/4 + 255)/256, 256, 0, stream>>>(
            in_w[dir], iw, D_IN_PROJ*D_MODEL/4);
        // 1. in_proj wide tile (split outputs): [z | xbcr], dt cols skipped
        mfma_gemm_wide<<<dim3(13, 64), 256, 0, stream>>>(
            xq_h, xq_l, D_MODEL, iw, D_MODEL, D_IN_PROJ, D_MODEL,
            lengths, dir, z, xbcr);
        // 1b. exact fp32 dt_raw -> la
        dt_exact_kernel<<<NROWS/4, 256, 0, stream>>>(
            x, in_w[dir] + (size_t)(D_INNER + CONV_DIM) * D_MODEL, lengths, dir, la);
        // 2. conv + silu + transpose + dt/cumsum
        conv_silu_fused_kernel<<<dim3(27, BATCH*NCHUNK), 256, 0, stream>>>(
            xbcr, conv_w[dir], conv_b[dir], xTh, xTl, bch, bcl,
            dt_bias[dir], A_log[dir], dtb, la);
        // 3. chunked SSD scan
        chunk_state_kernel<<<dim3(BATCH*NHEADS, NCHUNK), 256, 0, stream>>>(
            xTh, xTl, bch, bcl, la, dtb, hloc);
        combine_kernel<<<dim3(BATCH*NHEADS, 16), 256, 0, stream>>>(hloc, la);
        // 4. chunk_y with fused gate + norm_w + sqsum (pairs -> yg_p)
        hipMemsetAsync(sqs, 0, NROWS * sizeof(float), stream);
        chunk_y_kernel<<<dim3(BATCH*NHEADS, NCHUNK), 256, 0, stream>>>(
            xTh, xTl, bch, bcl, hloc, la, dtb, Dp[dir],
            z, norm_w[dir], yg_p, sqs);
        // 5. fused output projection: Wd = op_w[:, dir*768:+768] @ out_w
        prep_outw_kernel<<<NCONV_BLK + NT_BLK, 256, 0, stream>>>(
            op_w, out_w[dir], oph, opl, owTh);
        mfma_gemm<<<dim3(12, 6), 256, 0, stream>>>(
            oph + dir * D_MODEL, opl + dir * D_MODEL, 2*D_MODEL,
            owTh, D_MODEL, D_INNER, D_MODEL,
            lengths, 0, 0, 4,
            nullptr, D_INNER, nullptr, nullptr, wdp, nullptr, nullptr, nullptr);
        // 6. big out-GEMM with RMS scale: fwd writes rbuf, bwd adds flipped
        if (dir == 0) {
            mfma_gemm<<<dim3(6, 64), 256, 0, stream>>>(
                yg_p, yg_p + D_INNER, 3072, wdp, D_INNER,
                D_MODEL, D_INNER, lengths, 0, 0, 0,
                rbuf, D_MODEL, nullptr, nullptr, nullptr, op_b, x, sqs);
        } else {
            mfma_gemm<<<dim3(6, 64), 256, 0, stream>>>(
                yg_p, yg_p + D_INNER, 3072, wdp, D_INNER,
                D_MODEL, D_INNER, lengths, 0, 1, 3,
                rbuf, D_MODEL, nullptr, nullptr, nullptr, nullptr, nullptr, sqs);
        }
    }

    // layernorm -> out
    layernorm_kernel<<<NROWS, 256, 0, stream>>>(rbuf, ln_g, ln_b, outp);
}

// Round 18
// 753.557 us; speedup vs baseline: 1.0354x; 1.0354x over previous
//
#include <hip/hip_runtime.h>
#include <cstdint>
#include <cstddef>

#define D_MODEL   768
#define D_STATE   64
#define D_INNER   1536
#define HEADDIM   64
#define NHEADS    24
#define D_CONV    4
#define CONV_DIM  1664      // D_INNER + 2*D_STATE
#define D_IN_PROJ 3224      // 2*D_INNER + 2*D_STATE + NHEADS
#define BATCH     4
#define SEQLEN    2048
#define NROWS     (BATCH*SEQLEN)   // 8192
#define NCHUNK    32
#define Q         64               // chunk length

typedef unsigned short u16;
typedef __attribute__((ext_vector_type(8))) short bf16x8;
typedef __attribute__((ext_vector_type(8))) unsigned short u16x8;
typedef __attribute__((ext_vector_type(4))) float f32x4;

__device__ __forceinline__ int flip_row(int m, const int* __restrict__ lengths) {
    int b = m >> 11;
    int t = m & (SEQLEN - 1);
    int len = lengths[b];
    int ft = (t < len) ? (len - 1 - t) : t;
    return (b << 11) | ft;
}

__device__ __forceinline__ u16 f2bf(float f) {
    unsigned int u = __float_as_uint(f);
    unsigned int r = u + 0x7FFFu + ((u >> 16) & 1u);
    return (u16)(r >> 16);
}
__device__ __forceinline__ float bf2f(u16 h) {
    return __uint_as_float(((unsigned int)h) << 16);
}

// f32 -> (hi, lo) bf16 pair arrays
__global__ __launch_bounds__(256)
void convert_pair_kernel(const float* __restrict__ in, u16* __restrict__ hi,
                         u16* __restrict__ lo, int n4)
{
    int i = blockIdx.x * 256 + threadIdx.x;
    if (i >= n4) return;
    float4 v = *(const float4*)(in + (size_t)i * 4);
    ushort4 h, l;
    h.x = f2bf(v.x); l.x = f2bf(v.x - bf2f(h.x));
    h.y = f2bf(v.y); l.y = f2bf(v.y - bf2f(h.y));
    h.z = f2bf(v.z); l.z = f2bf(v.z - bf2f(h.z));
    h.w = f2bf(v.w); l.w = f2bf(v.w - bf2f(h.w));
    *(ushort4*)(hi + (size_t)i * 4) = h;
    *(ushort4*)(lo + (size_t)i * 4) = l;
}

// f32 -> single bf16 array
__global__ __launch_bounds__(256)
void convert_single_kernel(const float* __restrict__ in, u16* __restrict__ hi, int n4)
{
    int i = blockIdx.x * 256 + threadIdx.x;
    if (i >= n4) return;
    float4 v = *(const float4*)(in + (size_t)i * 4);
    ushort4 h;
    h.x = f2bf(v.x); h.y = f2bf(v.y); h.z = f2bf(v.z); h.w = f2bf(v.w);
    *(ushort4*)(hi + (size_t)i * 4) = h;
}

// prep for fused output projection: (a) op_w (768x1536) -> pairs (A-side of wd),
// (b) transpose out_w (768x1536) -> owT[1536][768] single bf16 (W-side of wd)
#define NCONV_BLK 1152    // 768*1536/4/256
#define NT_BLK    288     // 24 x 12 transpose tiles
__global__ __launch_bounds__(256)
void prep_outw_kernel(const float* __restrict__ op_w, const float* __restrict__ ow,
                      u16* __restrict__ oph, u16* __restrict__ opl,
                      u16* __restrict__ owTh)
{
    const int bid = blockIdx.x;
    const int tid = threadIdx.x;
    if (bid < NCONV_BLK) {
        int i = bid * 256 + tid;
        float4 v = *(const float4*)(op_w + (size_t)i * 4);
        ushort4 h, l;
        h.x = f2bf(v.x); l.x = f2bf(v.x - bf2f(h.x));
        h.y = f2bf(v.y); l.y = f2bf(v.y - bf2f(h.y));
        h.z = f2bf(v.z); l.z = f2bf(v.z - bf2f(h.z));
        h.w = f2bf(v.w); l.w = f2bf(v.w - bf2f(h.w));
        *(ushort4*)(oph + (size_t)i * 4) = h;
        *(ushort4*)(opl + (size_t)i * 4) = l;
        return;
    }
    __shared__ float T[64][65];
    const int tb = bid - NCONV_BLK;
    const int e0 = (tb % 24) * 64;
    const int d0 = (tb / 24) * 64;
    const int col = tid & 63, rg = tid >> 6;
    #pragma unroll
    for (int i = 0; i < 16; i++) {
        int r = rg + i * 4;
        T[r][col] = ow[(size_t)(d0 + r) * D_INNER + e0 + col];
    }
    __syncthreads();
    const int er = tid >> 2, dc0 = (tid & 3) * 16;
    u16x8 ph[2];
    #pragma unroll
    for (int j = 0; j < 16; j++)
        ph[j >> 3][j & 7] = f2bf(T[dc0 + j][er]);
    size_t obase = (size_t)(e0 + er) * D_MODEL + d0 + dc0;
    *(u16x8*)(owTh + obase)     = ph[0];
    *(u16x8*)(owTh + obase + 8) = ph[1];
}

// ---------- 2-term split-bf16 MFMA GEMM, BK=32, DOUBLE-BUFFERED LDS ----------
// (R16 version: best measured total)
// mode 0: C f32 = scale*acc + bias[n] + resid[m]
// mode 1: split store -> Cz | Cxbc
// mode 3: C[crow*ldc+n] += scale*acc
// mode 4: Cp[crow*ldc+n] = bf16(acc)
__global__ __launch_bounds__(256, 3)
void mfma_gemm(const u16* __restrict__ Ahi, const u16* __restrict__ Alo, int lda,
               const u16* __restrict__ W, int ldw,
               int N, int K, const int* __restrict__ lengths,
               int flipA, int flipC, int mode,
               float* __restrict__ C, int ldc,
               float* __restrict__ Cz, float* __restrict__ Cxbc,
               u16* __restrict__ Cp,
               const float* __restrict__ bias, const float* __restrict__ resid,
               const float* __restrict__ sqsum)
{
    __shared__ alignas(16) u16 lds[2 * 3 * 4096];   // [buf][matrix][4096]
    const int tid = threadIdx.x;
    const int m0 = blockIdx.y * 128;
    const int n0 = blockIdx.x * 128;
    const int lane = tid & 63;
    const int wid = tid >> 6;
    const int wm = wid >> 1, wn = wid & 1;

    const int kh = tid & 3;           // k-group (8 u16 each), 0..3
    const int rb = tid >> 2;          // 0..63
    int aoff[2], woff[2], lws[2];
    #pragma unroll
    for (int c = 0; c < 2; c++) {
        int row = rb + c * 64;
        int grow = m0 + row;
        if (flipA) grow = flip_row(grow, lengths);
        aoff[c] = grow * lda + kh * 8;
        int wrow = n0 + row; if (wrow >= N) wrow = N - 1;
        woff[c] = wrow * ldw + kh * 8;
        lws[c] = kh * 1024 + ((row & 0x78) | ((row ^ (kh << 1)) & 7)) * 8;
    }

    f32x4 acc[4][4];
    const f32x4 zero4 = {0.f, 0.f, 0.f, 0.f};
    #pragma unroll
    for (int i = 0; i < 4; i++)
        #pragma unroll
        for (int j = 0; j < 4; j++) acc[i][j] = zero4;

    const int l15 = lane & 15, lq = lane >> 4;
    const int arow0 = wm * 64 + l15;
    const int wrow0 = wn * 64 + l15;
    const int abase = lq * 1024 + ((arow0 & 0x78) | ((arow0 ^ (lq << 1)) & 7)) * 8;
    const int wbase = lq * 1024 + ((wrow0 & 0x78) | ((wrow0 ^ (lq << 1)) & 7)) * 8;

    // prologue: tile 0 -> buf0 ; prefetch tile 1 into regs
    u16x8 va[2], vb[2], vc[2];
    #pragma unroll
    for (int c = 0; c < 2; c++) {
        va[c] = *(const u16x8*)(Ahi + (size_t)aoff[c]);
        vb[c] = *(const u16x8*)(Alo + (size_t)aoff[c]);
        vc[c] = *(const u16x8*)(W   + (size_t)woff[c]);
    }
    #pragma unroll
    for (int c = 0; c < 2; c++) {
        *(u16x8*)(lds + 0 * 4096 + lws[c]) = va[c];
        *(u16x8*)(lds + 1 * 4096 + lws[c]) = vb[c];
        *(u16x8*)(lds + 2 * 4096 + lws[c]) = vc[c];
    }
    if (K > 32) {
        #pragma unroll
        for (int c = 0; c < 2; c++) {
            va[c] = *(const u16x8*)(Ahi + (size_t)aoff[c] + 32);
            vb[c] = *(const u16x8*)(Alo + (size_t)aoff[c] + 32);
            vc[c] = *(const u16x8*)(W   + (size_t)woff[c] + 32);
        }
    }
    __syncthreads();

    int cur = 0;
    for (int kt = 0; kt < K; kt += 32) {
        u16* Lc = lds + cur * 12288;
        if (kt + 32 < K) {
            u16* Ln = lds + (cur ^ 1) * 12288;
            #pragma unroll
            for (int c = 0; c < 2; c++) {           // stage tile k+1 -> other buf
                *(u16x8*)(Ln + 0 * 4096 + lws[c]) = va[c];
                *(u16x8*)(Ln + 1 * 4096 + lws[c]) = vb[c];
                *(u16x8*)(Ln + 2 * 4096 + lws[c]) = vc[c];
            }
            if (kt + 64 < K) {                      // prefetch tile k+2
                #pragma unroll
                for (int c = 0; c < 2; c++) {
                    va[c] = *(const u16x8*)(Ahi + (size_t)aoff[c] + kt + 64);
                    vb[c] = *(const u16x8*)(Alo + (size_t)aoff[c] + kt + 64);
                    vc[c] = *(const u16x8*)(W   + (size_t)woff[c] + kt + 64);
                }
            }
        }
        bf16x8 ah[4], al[4], wv[4];
        #pragma unroll
        for (int f = 0; f < 4; f++) {
            ah[f] = *(const bf16x8*)(Lc + 0 * 4096 + abase + f * 128);
            al[f] = *(const bf16x8*)(Lc + 1 * 4096 + abase + f * 128);
            wv[f] = *(const bf16x8*)(Lc + 2 * 4096 + wbase + f * 128);
        }
        #pragma unroll
        for (int fr = 0; fr < 4; fr++)
            #pragma unroll
            for (int fc = 0; fc < 4; fc++) {
                acc[fr][fc] = __builtin_amdgcn_mfma_f32_16x16x32_bf16(
                    ah[fr], wv[fc], acc[fr][fc], 0, 0, 0);
                acc[fr][fc] = __builtin_amdgcn_mfma_f32_16x16x32_bf16(
                    al[fr], wv[fc], acc[fr][fc], 0, 0, 0);
            }
        __syncthreads();                            // single barrier per K-step
        cur ^= 1;
    }

    #pragma unroll
    for (int fr = 0; fr < 4; fr++) {
        int mr[4], crow[4];
        float scl[4];
        #pragma unroll
        for (int r = 0; r < 4; r++) {
            mr[r] = m0 + wm * 64 + fr * 16 + lq * 4 + r;
            crow[r] = flipC ? flip_row(mr[r], lengths) : mr[r];
            scl[r] = sqsum ? rsqrtf(sqsum[mr[r]] * (1.f / D_INNER) + 1e-5f) : 1.f;
        }
        #pragma unroll
        for (int fc = 0; fc < 4; fc++) {
            const int nb = n0 + wn * 64 + fc * 16;
            const int nn = nb + l15;
            if (nn >= N) continue;
            #pragma unroll
            for (int r = 0; r < 4; r++) {
                float v = acc[fr][fc][r];
                if (mode == 1) {
                    if (nb < D_INNER)
                        Cz[(size_t)crow[r] * D_INNER + nn] = v;
                    else if (nb < D_INNER + CONV_DIM)
                        Cxbc[(size_t)crow[r] * CONV_DIM + (nn - D_INNER)] = v;
                    // dt columns handled exactly by dt_exact_kernel
                } else if (mode == 3) {
                    C[(size_t)crow[r] * ldc + nn] += v * scl[r];
                } else if (mode == 4) {
                    Cp[(size_t)crow[r] * ldc + nn] = f2bf(v);
                } else {
                    v = v * scl[r] + bias[nn] + resid[(size_t)mr[r] * D_MODEL + nn];
                    C[(size_t)crow[r] * ldc + nn] = v;
                }
            }
        }
    }
}

// exact fp32 dt_raw: la[row][h] = dot(x[fliprow], in_w[3200+h])  (24 heads)
__global__ __launch_bounds__(256)
void dt_exact_kernel(const float* __restrict__ x, const float* __restrict__ wdt,
                     const int* __restrict__ lengths, int flipA,
                     float* __restrict__ la)
{
    const int wv = threadIdx.x >> 6, lane = threadIdx.x & 63;
    const int row = blockIdx.x * 4 + wv;
    int grow = flipA ? flip_row(row, lengths) : row;
    const float* xr = x + (size_t)grow * D_MODEL;
    float xv[12];
    #pragma unroll
    for (int k = 0; k < 12; k++) xv[k] = xr[k * 64 + lane];
    for (int c = 0; c < NHEADS; c++) {
        const float* wr = wdt + (size_t)c * D_MODEL;
        float acc = 0.f;
        #pragma unroll
        for (int k = 0; k < 12; k++) acc = fmaf(xv[k], wr[k * 64 + lane], acc);
        #pragma unroll
        for (int o = 32; o > 0; o >>= 1) acc += __shfl_xor(acc, o);
        if (lane == 0) la[(size_t)row * NHEADS + c] = acc;
    }
}

// fused causal conv + silu + per-chunk transpose + (cg==26) dt/cumsum
__global__ __launch_bounds__(256)
void conv_silu_fused_kernel(const float* __restrict__ xbcr, const float* __restrict__ cw,
                            const float* __restrict__ cb,
                            u16* __restrict__ xTh, u16* __restrict__ xTl,
                            u16* __restrict__ bch, u16* __restrict__ bcl,
                            const float* __restrict__ dt_bias, const float* __restrict__ A_log,
                            float* __restrict__ dtb, float* __restrict__ la)
{
    __shared__ float T[64][65];
    const int cg = blockIdx.x;
    const int rc = blockIdx.y;
    const int tid = threadIdx.x;
    if (cg == 26) {
        const int lane2 = tid & 63, w = tid >> 6;
        const int row0 = rc * 64;
        #pragma unroll
        for (int i = 0; i < 6; i++) {
            int h = w * 6 + i;
            size_t idx = (size_t)(row0 + lane2) * NHEADS + h;
            float v = la[idx] + dt_bias[h];
            float sp = (v > 20.f) ? v : log1pf(expf(v));
            dtb[idx] = sp;
            float dA = sp * (-expf(A_log[h]));
            #pragma unroll
            for (int o = 1; o < 64; o <<= 1) {
                float u = __shfl_up(dA, o);
                if (lane2 >= o) dA += u;
            }
            la[idx] = dA;
        }
        return;
    }
    const int col = tid & 63, rg = tid >> 6;
    const int c = cg * 64 + col;
    const int rstart = rc * 64 + rg * 16;
    const int t0 = rstart & (SEQLEN - 1);
    const float c0 = cw[c*4+0], c1 = cw[c*4+1], c2 = cw[c*4+2], c3 = cw[c*4+3];
    const float cbv = cb[c];
    const float* base = xbcr + (size_t)rstart * CONV_DIM + c;
    float w0 = (t0 >= 3) ? base[-3 * CONV_DIM] : 0.f;
    float w1 = (t0 >= 2) ? base[-2 * CONV_DIM] : 0.f;
    float w2 = (t0 >= 1) ? base[-1 * CONV_DIM] : 0.f;
    const bool isx = (cg < 24);
    #pragma unroll
    for (int r = 0; r < 16; r++) {
        float w3 = base[r * CONV_DIM];
        float acc = cbv + w0*c0 + w1*c1 + w2*c2 + w3*c3;
        float val = acc / (1.f + expf(-acc));
        if (isx) {
            T[rg*16 + r][col] = val;
        } else {
            size_t gi = (size_t)(rstart + r) * 128 + (c - D_INNER);
            u16 hh = f2bf(val);
            bch[gi] = hh;
            bcl[gi] = f2bf(val - bf2f(hh));
        }
        w0 = w1; w1 = w2; w2 = w3;
    }
    if (!isx) return;
    __syncthreads();
    const int p = tid >> 2, s0 = (tid & 3) * 16;
    size_t tile = (size_t)(((rc >> 5) * NHEADS + cg) * NCHUNK + (rc & 31));
    size_t obase = tile * 4096 + p * 64 + s0;
    u16x8 ph[2], pl[2];
    #pragma unroll
    for (int j = 0; j < 16; j++) {
        float v = T[s0 + j][p];
        u16 hh = f2bf(v);
        ph[j >> 3][j & 7] = hh;
        pl[j >> 3][j & 7] = f2bf(v - bf2f(hh));
    }
    *(u16x8*)(xTh + obase)     = ph[0];
    *(u16x8*)(xTh + obase + 8) = ph[1];
    *(u16x8*)(xTl + obase)     = pl[0];
    *(u16x8*)(xTl + obase + 8) = pl[1];
}

// 2-term split-bf16 64x64x64 GEMM helper: A-side pairs (rA, rA+4096),
// W-side SINGLE bf16 (rW).  2 MFMA per fragment pair (was 3).
__device__ __forceinline__ void gemm2(const u16* rA, const u16* rW,
                                      int ar0, int wr0, int lq, f32x4 acc[2][2])
{
    #pragma unroll
    for (int kk = 0; kk < 2; kk++) {
        const int khs = kk * 4 + lq;
        const int ab = khs * 512 + ((ar0 & 0x38) | ((ar0 ^ khs) & 7)) * 8;
        const int wb = khs * 512 + ((wr0 & 0x38) | ((wr0 ^ khs) & 7)) * 8;
        bf16x8 ah[2], al[2], wh[2];
        #pragma unroll
        for (int f = 0; f < 2; f++) {
            ah[f] = *(const bf16x8*)(rA + ab + f * 128);
            al[f] = *(const bf16x8*)(rA + 4096 + ab + f * 128);
            wh[f] = *(const bf16x8*)(rW + wb + f * 128);
        }
        #pragma unroll
        for (int fr = 0; fr < 2; fr++)
            #pragma unroll
            for (int fc = 0; fc < 2; fc++) {
                acc[fr][fc] = __builtin_amdgcn_mfma_f32_16x16x32_bf16(ah[fr], wh[fc], acc[fr][fc], 0, 0, 0);
                acc[fr][fc] = __builtin_amdgcn_mfma_f32_16x16x32_bf16(al[fr], wh[fc], acc[fr][fc], 0, 0, 0);
            }
    }
}

// chunk state: S(p,n) = sum_s exp(la63-la[s]) dt[s] x[s][p] B[s][n]  -> hloc[tile]
// 2-term: A = xT pairs, W = (w*B) single bf16
__global__ __launch_bounds__(256)
void chunk_state_kernel(const u16* __restrict__ xTh, const u16* __restrict__ xTl,
                        const u16* __restrict__ bch, const u16* __restrict__ bcl,
                        const float* __restrict__ la, const float* __restrict__ dtb,
                        float* __restrict__ hloc)
{
    __shared__ alignas(16) u16 lA[2 * 4096];
    __shared__ alignas(16) u16 lW[4096];
    __shared__ float la_sh[64], w_sh[64];
    const int bh = blockIdx.x, c = blockIdx.y;
    const int b = bh / NHEADS, h = bh - b * NHEADS;
    const int row0 = b * SEQLEN + c * Q;
    const size_t tile = (size_t)(bh * NCHUNK + c);
    const int tid = threadIdx.x;

    if (tid < 64) la_sh[tid] = la[(size_t)(row0 + tid) * NHEADS + h];
    __syncthreads();
    if (tid < 64)
        w_sh[tid] = expf(la_sh[63] - la_sh[tid]) * dtb[(size_t)(row0 + tid) * NHEADS + h];
    {
        const int kh = tid & 7, rr = tid >> 3;
        #pragma unroll
        for (int cc = 0; cc < 2; cc++) {
            int row = rr + cc * 32;
            int lws = kh * 512 + ((row & 0x38) | ((row ^ kh) & 7)) * 8;
            *(u16x8*)(lA + lws)        = *(const u16x8*)(xTh + tile * 4096 + row * 64 + kh * 8);
            *(u16x8*)(lA + 4096 + lws) = *(const u16x8*)(xTl + tile * 4096 + row * 64 + kh * 8);
        }
    }
    __syncthreads();
    {
        const int n = tid & 63, sg = tid >> 6;
        #pragma unroll
        for (int i = 0; i < 16; i++) {
            int s = sg + i * 4;
            size_t gidx = (size_t)(row0 + s) * 128 + n;
            float bv = bf2f(bch[gidx]) + bf2f(bcl[gidx]);
            float v = bv * w_sh[s];
            int addr = (s >> 3) * 512 + ((n & 0x38) | ((n ^ (s >> 3)) & 7)) * 8 + (s & 7);
            lW[addr] = f2bf(v);
        }
    }
    __syncthreads();
    const int lane = tid & 63, wid = tid >> 6;
    const int wm = wid >> 1, wn = wid & 1;
    const int l15 = lane & 15, lq = lane >> 4;
    f32x4 acc[2][2];
    const f32x4 z4 = {0.f, 0.f, 0.f, 0.f};
    acc[0][0] = z4; acc[0][1] = z4; acc[1][0] = z4; acc[1][1] = z4;
    gemm2(lA, lW, wm * 32 + l15, wn * 32 + l15, lq, acc);
    #pragma unroll
    for (int fr = 0; fr < 2; fr++)
        #pragma unroll
        for (int fc = 0; fc < 2; fc++)
            #pragma unroll
            for (int r = 0; r < 4; r++) {
                int p = wm * 32 + fr * 16 + lq * 4 + r;
                int n = wn * 32 + fc * 16 + l15;
                hloc[tile * 4096 + p * 64 + n] = acc[fr][fc][r];
            }
}

// in-place sequential fold: hloc[c] := state ENTERING chunk c
// grid (96 bh, 16 p-slices) x 256 threads
__global__ __launch_bounds__(256)
void combine_kernel(float* __restrict__ hloc, const float* __restrict__ la)
{
    const int bh = blockIdx.x;
    const int b = bh / NHEADS, h = bh - b * NHEADS;
    const int off = blockIdx.y * 256 + threadIdx.x;
    float run = 0.f;
    for (int c = 0; c < NCHUNK; c++) {
        float* ptr = hloc + ((size_t)(bh * NCHUNK + c)) * 4096 + off;
        float sv = *ptr;
        *ptr = run;
        float cd = expf(la[(size_t)(b * SEQLEN + c * Q + Q - 1) * NHEADS + h]);
        run = fmaf(run, cd, sv);
    }
}

// chunk y + fused gate/norm_w/sqsum, 2-term gemms:
// acc2: A=C pairs, W=hin single; accG: A=C pairs, W=B single;
// acc1: A=P pairs,  W=x single.
__global__ __launch_bounds__(256)
void chunk_y_kernel(const u16* __restrict__ xTh, const u16* __restrict__ xTl,
                    const u16* __restrict__ bch, const u16* __restrict__ bcl,
                    const float* __restrict__ hloc, const float* __restrict__ la,
                    const float* __restrict__ dtb, const float* __restrict__ Dp,
                    const float* __restrict__ z, const float* __restrict__ norm_w,
                    u16* __restrict__ ygp, float* __restrict__ sqsum)
{
    __shared__ alignas(16) u16 r1[2 * 4096];   // C pairs -> P pairs
    __shared__ alignas(16) u16 r2[4096];       // hin -> B -> x (all single)
    __shared__ float la_sh[64], dt_sh[64], ssh[64];
    const int bh = blockIdx.x, c = blockIdx.y;
    const int b = bh / NHEADS, h = bh - b * NHEADS;
    const int row0 = b * SEQLEN + c * Q;
    const size_t tile = (size_t)(bh * NCHUNK + c);
    const int tid = threadIdx.x;
    if (tid < 64) {
        la_sh[tid] = la[(size_t)(row0 + tid) * NHEADS + h];
        dt_sh[tid] = dtb[(size_t)(row0 + tid) * NHEADS + h];
        ssh[tid] = 0.f;
    }
    const int kh = tid & 7, rr = tid >> 3;
    #pragma unroll
    for (int cc = 0; cc < 2; cc++) {
        int row = rr + cc * 32;
        int lws = kh * 512 + ((row & 0x38) | ((row ^ kh) & 7)) * 8;
        *(u16x8*)(r1 + lws)        = *(const u16x8*)(bch + (size_t)(row0 + row) * 128 + 64 + kh * 8);
        *(u16x8*)(r1 + 4096 + lws) = *(const u16x8*)(bcl + (size_t)(row0 + row) * 128 + 64 + kh * 8);
        float4 f0 = *(const float4*)(hloc + tile * 4096 + row * 64 + kh * 8);
        float4 f1 = *(const float4*)(hloc + tile * 4096 + row * 64 + kh * 8 + 4);
        float vals[8] = {f0.x, f0.y, f0.z, f0.w, f1.x, f1.y, f1.z, f1.w};
        u16x8 hh;
        #pragma unroll
        for (int j = 0; j < 8; j++) hh[j] = f2bf(vals[j]);
        *(u16x8*)(r2 + lws) = hh;
    }
    __syncthreads();
    const int lane = tid & 63, wid = tid >> 6;
    const int wm = wid >> 1, wn = wid & 1;
    const int l15 = lane & 15, lq = lane >> 4;
    const int ar0 = wm * 32 + l15, wr0 = wn * 32 + l15;
    const f32x4 z4 = {0.f, 0.f, 0.f, 0.f};
    f32x4 acc2[2][2];
    acc2[0][0] = z4; acc2[0][1] = z4; acc2[1][0] = z4; acc2[1][1] = z4;
    gemm2(r1, r2, ar0, wr0, lq, acc2);
    __syncthreads();
    #pragma unroll
    for (int cc = 0; cc < 2; cc++) {
        int row = rr + cc * 32;
        int lws = kh * 512 + ((row & 0x38) | ((row ^ kh) & 7)) * 8;
        *(u16x8*)(r2 + lws) = *(const u16x8*)(bch + (size_t)(row0 + row) * 128 + kh * 8);
    }
    __syncthreads();
    f32x4 accG[2][2];
    accG[0][0] = z4; accG[0][1] = z4; accG[1][0] = z4; accG[1][1] = z4;
    gemm2(r1, r2, ar0, wr0, lq, accG);
    __syncthreads();
    const float Dph = Dp[h];
    #pragma unroll
    for (int fr = 0; fr < 2; fr++)
        #pragma unroll
        for (int fc = 0; fc < 2; fc++)
            #pragma unroll
            for (int r = 0; r < 4; r++) {
                int t = wm * 32 + fr * 16 + lq * 4 + r;
                int s = wn * 32 + fc * 16 + l15;
                float v = 0.f;
                if (s <= t) v = accG[fr][fc][r] * expf(la_sh[t] - la_sh[s]) * dt_sh[s];
                if (s == t) v += Dph;
                u16 hh = f2bf(v), ll = f2bf(v - bf2f(hh));
                int addr = (s >> 3) * 512 + ((t & 0x38) | ((t ^ (s >> 3)) & 7)) * 8 + (s & 7);
                r1[addr] = hh;
                r1[4096 + addr] = ll;
            }
    #pragma unroll
    for (int cc = 0; cc < 2; cc++) {
        int row = rr + cc * 32;
        int lws = kh * 512 + ((row & 0x38) | ((row ^ kh) & 7)) * 8;
        *(u16x8*)(r2 + lws) = *(const u16x8*)(xTh + tile * 4096 + row * 64 + kh * 8);
    }
    __syncthreads();
    f32x4 acc1[2][2];
    acc1[0][0] = z4; acc1[0][1] = z4; acc1[1][0] = z4; acc1[1][1] = z4;
    gemm2(r1, r2, ar0, wr0, lq, acc1);
    // fused epilogue: gate + norm_w + pair store + sqsum
    #pragma unroll
    for (int fr = 0; fr < 2; fr++)
        #pragma unroll
        for (int r = 0; r < 4; r++) {
            int t = wm * 32 + fr * 16 + lq * 4 + r;
            size_t row = row0 + t;
            float Et = expf(la_sh[t]);
            float s2 = 0.f;
            #pragma unroll
            for (int fc = 0; fc < 2; fc++) {
                int hp = h * 64 + wn * 32 + fc * 16 + l15;
                float yv = acc1[fr][fc][r] + Et * acc2[fr][fc][r];
                float zv = z[row * D_INNER + hp];
                float gv = yv * (zv / (1.f + expf(-zv)));
                s2 = fmaf(gv, gv, s2);
                float gn = gv * norm_w[hp];
                u16 hh = f2bf(gn);
                ygp[row * 3072 + hp] = hh;
                ygp[row * 3072 + 1536 + hp] = f2bf(gn - bf2f(hh));
            }
            s2 += __shfl_xor(s2, 1);
            s2 += __shfl_xor(s2, 2);
            s2 += __shfl_xor(s2, 4);
            s2 += __shfl_xor(s2, 8);
            if (l15 == 0) atomicAdd(&ssh[t], s2);
        }
    __syncthreads();
    if (tid < 64) atomicAdd(&sqsum[row0 + tid], ssh[tid]);
}

__global__ __launch_bounds__(256)
void layernorm_kernel(const float* __restrict__ r, const float* __restrict__ gam,
                      const float* __restrict__ bet, float* __restrict__ out)
{
    const int row = blockIdx.x;
    const float* rr = r + (size_t)row * D_MODEL;
    const int tid = threadIdx.x;
    float v[3];
    float s = 0.f, s2 = 0.f;
    #pragma unroll
    for (int i = 0; i < 3; i++) {
        v[i] = rr[tid + i * 256];
        s += v[i];
        s2 = fmaf(v[i], v[i], s2);
    }
    #pragma unroll
    for (int o = 32; o > 0; o >>= 1) { s += __shfl_xor(s, o); s2 += __shfl_xor(s2, o); }
    __shared__ float rs[4], rs2[4];
    if ((tid & 63) == 0) { rs[tid >> 6] = s; rs2[tid >> 6] = s2; }
    __syncthreads();
    float S  = rs[0] + rs[1] + rs[2] + rs[3];
    float S2 = rs2[0] + rs2[1] + rs2[2] + rs2[3];
    float mu  = S * (1.f / D_MODEL);
    float var = S2 * (1.f / D_MODEL) - mu * mu;
    float inv = rsqrtf(var + 1e-5f);
    #pragma unroll
    for (int i = 0; i < 3; i++) {
        int e = tid + i * 256;
        out[(size_t)row * D_MODEL + e] = (v[i] - mu) * inv * gam[e] + bet[e];
    }
}

extern "C" void kernel_launch(void* const* d_in, const int* in_sizes, int n_in,
                              void* d_out, int out_size, void* d_ws, size_t ws_size,
                              hipStream_t stream)
{
    const float* x        = (const float*)d_in[0];
    const int*   lengths  = (const int*)d_in[1];
    const float* in_w[2]    = {(const float*)d_in[2],  (const float*)d_in[10]};
    const float* conv_w[2]  = {(const float*)d_in[3],  (const float*)d_in[11]};
    const float* conv_b[2]  = {(const float*)d_in[4],  (const float*)d_in[12]};
    const float* dt_bias[2] = {(const float*)d_in[5],  (const float*)d_in[13]};
    const float* A_log[2]   = {(const float*)d_in[6],  (const float*)d_in[14]};
    const float* Dp[2]      = {(const float*)d_in[7],  (const float*)d_in[15]};
    const float* norm_w[2]  = {(const float*)d_in[8],  (const float*)d_in[16]};
    const float* out_w[2]   = {(const float*)d_in[9],  (const float*)d_in[17]};
    const float* op_w = (const float*)d_in[18];
    const float* op_b = (const float*)d_in[19];
    const float* ln_g = (const float*)d_in[20];
    const float* ln_b = (const float*)d_in[21];
    float* outp = (float*)d_out;

    // ---- workspace layout (same 262.4 MB footprint) ----
    float* z    = (float*)d_ws;                               // R0: 8192*1536
    float* xbcr = z + (size_t)NROWS * D_INNER;                // R1: 8192*1664 (-> hloc)
    float* la   = xbcr + (size_t)NROWS * CONV_DIM;            // R2a
    float* dtb  = la  + (size_t)NROWS * NHEADS;               // R2b
    float* sqs  = dtb + (size_t)NROWS * NHEADS;               // R2c: 8192 f32 (sqsum)
    u16*  xTh   = (u16*)(sqs + (size_t)NROWS * NHEADS);       // R3
    u16*  xTl   = xTh + (size_t)NROWS * D_INNER;
    u16*  bch   = xTl + (size_t)NROWS * D_INNER;
    u16*  bcl   = bch + (size_t)NROWS * 128;
    float* ybuf = (float*)(bcl + (size_t)NROWS * 128);        // R4
    u16*  R5    = (u16*)(ybuf + (size_t)NROWS * D_INNER);     // R5

    float* hloc  = xbcr;          // after conv, xbcr dead -> chunk states

    // R5: persistent x pairs + final residual
    u16*  xq_h = R5;
    u16*  xq_l = R5 + (size_t)NROWS * D_MODEL;
    float* rbuf = (float*)(R5 + 2 * (size_t)NROWS * D_MODEL);

    // per-dir transient: in_w single bf16 in R4 (dead until chunk_y)
    u16* iw   = (u16*)ybuf;
    u16* yg_p = (u16*)ybuf;

    // per-dir out-proj prep in R3 (dead after chunk_y)
    u16* oph  = xTh;
    u16* opl  = oph  + (size_t)D_MODEL * D_INNER;
    u16* owTh = opl  + (size_t)D_MODEL * D_INNER;
    u16* wdp  = owTh + (size_t)D_MODEL * D_INNER;   // 768 x 1536 single bf16

    size_t need = ((size_t)NROWS * (D_INNER + CONV_DIM + 3*NHEADS + CONV_DIM +
                                    D_INNER + D_INNER)) * sizeof(float);
    if (ws_size < need) return;

    // x pairs once (flip handled by GEMM row indexing)
    convert_pair_kernel<<<(NROWS*D_MODEL/4 + 255)/256, 256, 0, stream>>>(
        x, xq_h, xq_l, NROWS*D_MODEL/4);

    for (int dir = 0; dir < 2; dir++) {
        // 0. convert in_w single bf16 (R4)
        convert_single_kernel<<<(D_IN_PROJ*D_MODEL/4 + 255)/256, 256, 0, stream>>>(
            in_w[dir], iw, D_IN_PROJ*D_MODEL/4);
        // 1. in_proj (split outputs): [z | xbcr], dt cols skipped
        mfma_gemm<<<dim3(26, 64), 256, 0, stream>>>(
            xq_h, xq_l, D_MODEL, iw, D_MODEL, D_IN_PROJ, D_MODEL,
            lengths, dir, 0, 1,
            nullptr, 0, z, xbcr, nullptr, nullptr, nullptr, nullptr);
        // 1b. exact fp32 dt_raw -> la
        dt_exact_kernel<<<NROWS/4, 256, 0, stream>>>(
            x, in_w[dir] + (size_t)(D_INNER + CONV_DIM) * D_MODEL, lengths, dir, la);
        // 2. conv + silu + transpose + dt/cumsum
        conv_silu_fused_kernel<<<dim3(27, BATCH*NCHUNK), 256, 0, stream>>>(
            xbcr, conv_w[dir], conv_b[dir], xTh, xTl, bch, bcl,
            dt_bias[dir], A_log[dir], dtb, la);
        // 3. chunked SSD scan
        chunk_state_kernel<<<dim3(BATCH*NHEADS, NCHUNK), 256, 0, stream>>>(
            xTh, xTl, bch, bcl, la, dtb, hloc);
        combine_kernel<<<dim3(BATCH*NHEADS, 16), 256, 0, stream>>>(hloc, la);
        // 4. chunk_y with fused gate + norm_w + sqsum (pairs -> yg_p)
        hipMemsetAsync(sqs, 0, NROWS * sizeof(float), stream);
        chunk_y_kernel<<<dim3(BATCH*NHEADS, NCHUNK), 256, 0, stream>>>(
            xTh, xTl, bch, bcl, hloc, la, dtb, Dp[dir],
            z, norm_w[dir], yg_p, sqs);
        // 5. fused output projection: Wd = op_w[:, dir*768:+768] @ out_w
        prep_outw_kernel<<<NCONV_BLK + NT_BLK, 256, 0, stream>>>(
            op_w, out_w[dir], oph, opl, owTh);
        mfma_gemm<<<dim3(12, 6), 256, 0, stream>>>(
            oph + dir * D_MODEL, opl + dir * D_MODEL, 2*D_MODEL,
            owTh, D_MODEL, D_INNER, D_MODEL,
            lengths, 0, 0, 4,
            nullptr, D_INNER, nullptr, nullptr, wdp, nullptr, nullptr, nullptr);
        // 6. big out-GEMM with RMS scale: fwd writes rbuf, bwd adds flipped
        if (dir == 0) {
            mfma_gemm<<<dim3(6, 64), 256, 0, stream>>>(
                yg_p, yg_p + D_INNER, 3072, wdp, D_INNER,
                D_MODEL, D_INNER, lengths, 0, 0, 0,
                rbuf, D_MODEL, nullptr, nullptr, nullptr, op_b, x, sqs);
        } else {
            mfma_gemm<<<dim3(6, 64), 256, 0, stream>>>(
                yg_p, yg_p + D_INNER, 3072, wdp, D_INNER,
                D_MODEL, D_INNER, lengths, 0, 1, 3,
                rbuf, D_MODEL, nullptr, nullptr, nullptr, nullptr, nullptr, sqs);
        }
    }

    // layernorm -> out
    layernorm_kernel<<<NROWS, 256, 0, stream>>>(rbuf, ln_g, ln_b, outp);
}

// Round 19
// 617.266 us; speedup vs baseline: 1.2640x; 1.2208x over previous
//
#include <hip/hip_runtime.h>
#include <cstdint>
#include <cstddef>

#define D_MODEL   768
#define D_STATE   64
#define D_INNER   1536
#define HEADDIM   64
#define NHEADS    24
#define D_CONV    4
#define CONV_DIM  1664      // D_INNER + 2*D_STATE
#define D_IN_PROJ 3224      // 2*D_INNER + 2*D_STATE + NHEADS
#define BATCH     4
#define SEQLEN    2048
#define NROWS     (BATCH*SEQLEN)   // 8192
#define NCHUNK    32
#define Q         64               // chunk length

typedef unsigned short u16;
typedef __attribute__((ext_vector_type(8))) short bf16x8;
typedef __attribute__((ext_vector_type(8))) unsigned short u16x8;
typedef __attribute__((ext_vector_type(4))) float f32x4;

__device__ __forceinline__ int flip_row(int m, const int* __restrict__ lengths) {
    int b = m >> 11;
    int t = m & (SEQLEN - 1);
    int len = lengths[b];
    int ft = (t < len) ? (len - 1 - t) : t;
    return (b << 11) | ft;
}

__device__ __forceinline__ u16 f2bf(float f) {
    unsigned int u = __float_as_uint(f);
    unsigned int r = u + 0x7FFFu + ((u >> 16) & 1u);
    return (u16)(r >> 16);
}
__device__ __forceinline__ float bf2f(u16 h) {
    return __uint_as_float(((unsigned int)h) << 16);
}

// f32 -> single bf16 array
__global__ __launch_bounds__(256)
void convert_single_kernel(const float* __restrict__ in, u16* __restrict__ hi, int n4)
{
    int i = blockIdx.x * 256 + threadIdx.x;
    if (i >= n4) return;
    float4 v = *(const float4*)(in + (size_t)i * 4);
    ushort4 h;
    h.x = f2bf(v.x); h.y = f2bf(v.y); h.z = f2bf(v.z); h.w = f2bf(v.w);
    *(ushort4*)(hi + (size_t)i * 4) = h;
}

// prep for fused output projection: (a) op_w (768x1536) -> single bf16,
// (b) transpose out_w (768x1536) -> owT[1536][768] single bf16
#define NCONV_BLK 1152    // 768*1536/4/256
#define NT_BLK    288     // 24 x 12 transpose tiles
__global__ __launch_bounds__(256)
void prep_outw_kernel(const float* __restrict__ op_w, const float* __restrict__ ow,
                      u16* __restrict__ oph, u16* __restrict__ owTh)
{
    const int bid = blockIdx.x;
    const int tid = threadIdx.x;
    if (bid < NCONV_BLK) {
        int i = bid * 256 + tid;
        float4 v = *(const float4*)(op_w + (size_t)i * 4);
        ushort4 h;
        h.x = f2bf(v.x); h.y = f2bf(v.y); h.z = f2bf(v.z); h.w = f2bf(v.w);
        *(ushort4*)(oph + (size_t)i * 4) = h;
        return;
    }
    __shared__ float T[64][65];
    const int tb = bid - NCONV_BLK;
    const int e0 = (tb % 24) * 64;
    const int d0 = (tb / 24) * 64;
    const int col = tid & 63, rg = tid >> 6;
    #pragma unroll
    for (int i = 0; i < 16; i++) {
        int r = rg + i * 4;
        T[r][col] = ow[(size_t)(d0 + r) * D_INNER + e0 + col];
    }
    __syncthreads();
    const int er = tid >> 2, dc0 = (tid & 3) * 16;
    u16x8 ph[2];
    #pragma unroll
    for (int j = 0; j < 16; j++)
        ph[j >> 3][j & 7] = f2bf(T[dc0 + j][er]);
    size_t obase = (size_t)(e0 + er) * D_MODEL + d0 + dc0;
    *(u16x8*)(owTh + obase)     = ph[0];
    *(u16x8*)(owTh + obase + 8) = ph[1];
}

// ---------- single-bf16 MFMA GEMM, BK=32, DOUBLE-BUFFERED LDS ----------
// 128x128 tile, 256 threads = 4 waves (2x2), 4x4 16x16 frags/wave.
// A and W both single bf16 -> 16 MFMA per K-step per wave.
// LDS 32 KB = 2 buffers x (2 matrices x 8 KB) -> 5 blocks/CU.
// Swizzle: verified conflict-free map (row ^ (kh<<1))&7, kh in 0..3.
// mode 0: C f32 = scale*acc + bias[n] + resid[m]       (scale from sqsum)
// mode 1: split store -> Cz | Cxbc  (dt columns handled by dt_exact)
// mode 3: C[crow*ldc+n] += scale*acc (sequential launches only)
// mode 4: Cp[crow*ldc+n] = bf16(acc)
__global__ __launch_bounds__(256, 4)
void mfma_gemm(const u16* __restrict__ A, int lda,
               const u16* __restrict__ W, int ldw,
               int N, int K, const int* __restrict__ lengths,
               int flipA, int flipC, int mode,
               float* __restrict__ C, int ldc,
               float* __restrict__ Cz, float* __restrict__ Cxbc,
               u16* __restrict__ Cp,
               const float* __restrict__ bias, const float* __restrict__ resid,
               const float* __restrict__ sqsum)
{
    __shared__ alignas(16) u16 lds[2 * 2 * 4096];   // [buf][matrix][4096]
    const int tid = threadIdx.x;
    const int m0 = blockIdx.y * 128;
    const int n0 = blockIdx.x * 128;
    const int lane = tid & 63;
    const int wid = tid >> 6;
    const int wm = wid >> 1, wn = wid & 1;

    const int kh = tid & 3;           // k-group (8 u16 each), 0..3
    const int rb = tid >> 2;          // 0..63
    int aoff[2], woff[2], lws[2];
    #pragma unroll
    for (int c = 0; c < 2; c++) {
        int row = rb + c * 64;
        int grow = m0 + row;
        if (flipA) grow = flip_row(grow, lengths);
        aoff[c] = grow * lda + kh * 8;
        int wrow = n0 + row; if (wrow >= N) wrow = N - 1;
        woff[c] = wrow * ldw + kh * 8;
        lws[c] = kh * 1024 + ((row & 0x78) | ((row ^ (kh << 1)) & 7)) * 8;
    }

    f32x4 acc[4][4];
    const f32x4 zero4 = {0.f, 0.f, 0.f, 0.f};
    #pragma unroll
    for (int i = 0; i < 4; i++)
        #pragma unroll
        for (int j = 0; j < 4; j++) acc[i][j] = zero4;

    const int l15 = lane & 15, lq = lane >> 4;
    const int arow0 = wm * 64 + l15;
    const int wrow0 = wn * 64 + l15;
    const int abase = lq * 1024 + ((arow0 & 0x78) | ((arow0 ^ (lq << 1)) & 7)) * 8;
    const int wbase = lq * 1024 + ((wrow0 & 0x78) | ((wrow0 ^ (lq << 1)) & 7)) * 8;

    // prologue: tile 0 -> buf0 ; prefetch tile 1 into regs
    u16x8 va[2], vc[2];
    #pragma unroll
    for (int c = 0; c < 2; c++) {
        va[c] = *(const u16x8*)(A + (size_t)aoff[c]);
        vc[c] = *(const u16x8*)(W + (size_t)woff[c]);
    }
    #pragma unroll
    for (int c = 0; c < 2; c++) {
        *(u16x8*)(lds + 0 * 4096 + lws[c]) = va[c];
        *(u16x8*)(lds + 1 * 4096 + lws[c]) = vc[c];
    }
    if (K > 32) {
        #pragma unroll
        for (int c = 0; c < 2; c++) {
            va[c] = *(const u16x8*)(A + (size_t)aoff[c] + 32);
            vc[c] = *(const u16x8*)(W + (size_t)woff[c] + 32);
        }
    }
    __syncthreads();

    int cur = 0;
    for (int kt = 0; kt < K; kt += 32) {
        u16* Lc = lds + cur * 8192;
        if (kt + 32 < K) {
            u16* Ln = lds + (cur ^ 1) * 8192;
            #pragma unroll
            for (int c = 0; c < 2; c++) {           // stage tile k+1 -> other buf
                *(u16x8*)(Ln + 0 * 4096 + lws[c]) = va[c];
                *(u16x8*)(Ln + 1 * 4096 + lws[c]) = vc[c];
            }
            if (kt + 64 < K) {                      // prefetch tile k+2
                #pragma unroll
                for (int c = 0; c < 2; c++) {
                    va[c] = *(const u16x8*)(A + (size_t)aoff[c] + kt + 64);
                    vc[c] = *(const u16x8*)(W + (size_t)woff[c] + kt + 64);
                }
            }
        }
        bf16x8 ah[4], wv[4];
        #pragma unroll
        for (int f = 0; f < 4; f++) {
            ah[f] = *(const bf16x8*)(Lc + 0 * 4096 + abase + f * 128);
            wv[f] = *(const bf16x8*)(Lc + 1 * 4096 + wbase + f * 128);
        }
        #pragma unroll
        for (int fr = 0; fr < 4; fr++)
            #pragma unroll
            for (int fc = 0; fc < 4; fc++)
                acc[fr][fc] = __builtin_amdgcn_mfma_f32_16x16x32_bf16(
                    ah[fr], wv[fc], acc[fr][fc], 0, 0, 0);
        __syncthreads();                            // single barrier per K-step
        cur ^= 1;
    }

    #pragma unroll
    for (int fr = 0; fr < 4; fr++) {
        int mr[4], crow[4];
        float scl[4];
        #pragma unroll
        for (int r = 0; r < 4; r++) {
            mr[r] = m0 + wm * 64 + fr * 16 + lq * 4 + r;
            crow[r] = flipC ? flip_row(mr[r], lengths) : mr[r];
            scl[r] = sqsum ? rsqrtf(sqsum[mr[r]] * (1.f / D_INNER) + 1e-5f) : 1.f;
        }
        #pragma unroll
        for (int fc = 0; fc < 4; fc++) {
            const int nb = n0 + wn * 64 + fc * 16;
            const int nn = nb + l15;
            if (nn >= N) continue;
            #pragma unroll
            for (int r = 0; r < 4; r++) {
                float v = acc[fr][fc][r];
                if (mode == 1) {
                    if (nb < D_INNER)
                        Cz[(size_t)crow[r] * D_INNER + nn] = v;
                    else if (nb < D_INNER + CONV_DIM)
                        Cxbc[(size_t)crow[r] * CONV_DIM + (nn - D_INNER)] = v;
                    // dt columns handled exactly by dt_exact_kernel
                } else if (mode == 3) {
                    C[(size_t)crow[r] * ldc + nn] += v * scl[r];
                } else if (mode == 4) {
                    Cp[(size_t)crow[r] * ldc + nn] = f2bf(v);
                } else {
                    v = v * scl[r] + bias[nn] + resid[(size_t)mr[r] * D_MODEL + nn];
                    C[(size_t)crow[r] * ldc + nn] = v;
                }
            }
        }
    }
}

// exact fp32 dt_raw: la[row][h] = dot(x[fliprow], in_w[3200+h])  (24 heads)
__global__ __launch_bounds__(256)
void dt_exact_kernel(const float* __restrict__ x, const float* __restrict__ wdt,
                     const int* __restrict__ lengths, int flipA,
                     float* __restrict__ la)
{
    const int wv = threadIdx.x >> 6, lane = threadIdx.x & 63;
    const int row = blockIdx.x * 4 + wv;
    int grow = flipA ? flip_row(row, lengths) : row;
    const float* xr = x + (size_t)grow * D_MODEL;
    float xv[12];
    #pragma unroll
    for (int k = 0; k < 12; k++) xv[k] = xr[k * 64 + lane];
    for (int c = 0; c < NHEADS; c++) {
        const float* wr = wdt + (size_t)c * D_MODEL;
        float acc = 0.f;
        #pragma unroll
        for (int k = 0; k < 12; k++) acc = fmaf(xv[k], wr[k * 64 + lane], acc);
        #pragma unroll
        for (int o = 32; o > 0; o >>= 1) acc += __shfl_xor(acc, o);
        if (lane == 0) la[(size_t)row * NHEADS + c] = acc;
    }
}

// fused causal conv + silu + per-chunk transpose + (cg==26) dt/cumsum
__global__ __launch_bounds__(256)
void conv_silu_fused_kernel(const float* __restrict__ xbcr, const float* __restrict__ cw,
                            const float* __restrict__ cb,
                            u16* __restrict__ xTh, u16* __restrict__ xTl,
                            u16* __restrict__ bch, u16* __restrict__ bcl,
                            const float* __restrict__ dt_bias, const float* __restrict__ A_log,
                            float* __restrict__ dtb, float* __restrict__ la)
{
    __shared__ float T[64][65];
    const int cg = blockIdx.x;
    const int rc = blockIdx.y;
    const int tid = threadIdx.x;
    if (cg == 26) {
        const int lane2 = tid & 63, w = tid >> 6;
        const int row0 = rc * 64;
        #pragma unroll
        for (int i = 0; i < 6; i++) {
            int h = w * 6 + i;
            size_t idx = (size_t)(row0 + lane2) * NHEADS + h;
            float v = la[idx] + dt_bias[h];
            float sp = (v > 20.f) ? v : log1pf(expf(v));
            dtb[idx] = sp;
            float dA = sp * (-expf(A_log[h]));
            #pragma unroll
            for (int o = 1; o < 64; o <<= 1) {
                float u = __shfl_up(dA, o);
                if (lane2 >= o) dA += u;
            }
            la[idx] = dA;
        }
        return;
    }
    const int col = tid & 63, rg = tid >> 6;
    const int c = cg * 64 + col;
    const int rstart = rc * 64 + rg * 16;
    const int t0 = rstart & (SEQLEN - 1);
    const float c0 = cw[c*4+0], c1 = cw[c*4+1], c2 = cw[c*4+2], c3 = cw[c*4+3];
    const float cbv = cb[c];
    const float* base = xbcr + (size_t)rstart * CONV_DIM + c;
    float w0 = (t0 >= 3) ? base[-3 * CONV_DIM] : 0.f;
    float w1 = (t0 >= 2) ? base[-2 * CONV_DIM] : 0.f;
    float w2 = (t0 >= 1) ? base[-1 * CONV_DIM] : 0.f;
    const bool isx = (cg < 24);
    #pragma unroll
    for (int r = 0; r < 16; r++) {
        float w3 = base[r * CONV_DIM];
        float acc = cbv + w0*c0 + w1*c1 + w2*c2 + w3*c3;
        float val = acc / (1.f + expf(-acc));
        if (isx) {
            T[rg*16 + r][col] = val;
        } else {
            size_t gi = (size_t)(rstart + r) * 128 + (c - D_INNER);
            u16 hh = f2bf(val);
            bch[gi] = hh;
            bcl[gi] = f2bf(val - bf2f(hh));
        }
        w0 = w1; w1 = w2; w2 = w3;
    }
    if (!isx) return;
    __syncthreads();
    const int p = tid >> 2, s0 = (tid & 3) * 16;
    size_t tile = (size_t)(((rc >> 5) * NHEADS + cg) * NCHUNK + (rc & 31));
    size_t obase = tile * 4096 + p * 64 + s0;
    u16x8 ph[2], pl[2];
    #pragma unroll
    for (int j = 0; j < 16; j++) {
        float v = T[s0 + j][p];
        u16 hh = f2bf(v);
        ph[j >> 3][j & 7] = hh;
        pl[j >> 3][j & 7] = f2bf(v - bf2f(hh));
    }
    *(u16x8*)(xTh + obase)     = ph[0];
    *(u16x8*)(xTh + obase + 8) = ph[1];
    *(u16x8*)(xTl + obase)     = pl[0];
    *(u16x8*)(xTl + obase + 8) = pl[1];
}

// 2-term split-bf16 64x64x64 GEMM helper: A-side pairs (rA, rA+4096),
// W-side SINGLE bf16 (rW).  2 MFMA per fragment pair.
__device__ __forceinline__ void gemm2(const u16* rA, const u16* rW,
                                      int ar0, int wr0, int lq, f32x4 acc[2][2])
{
    #pragma unroll
    for (int kk = 0; kk < 2; kk++) {
        const int khs = kk * 4 + lq;
        const int ab = khs * 512 + ((ar0 & 0x38) | ((ar0 ^ khs) & 7)) * 8;
        const int wb = khs * 512 + ((wr0 & 0x38) | ((wr0 ^ khs) & 7)) * 8;
        bf16x8 ah[2], al[2], wh[2];
        #pragma unroll
        for (int f = 0; f < 2; f++) {
            ah[f] = *(const bf16x8*)(rA + ab + f * 128);
            al[f] = *(const bf16x8*)(rA + 4096 + ab + f * 128);
            wh[f] = *(const bf16x8*)(rW + wb + f * 128);
        }
        #pragma unroll
        for (int fr = 0; fr < 2; fr++)
            #pragma unroll
            for (int fc = 0; fc < 2; fc++) {
                acc[fr][fc] = __builtin_amdgcn_mfma_f32_16x16x32_bf16(ah[fr], wh[fc], acc[fr][fc], 0, 0, 0);
                acc[fr][fc] = __builtin_amdgcn_mfma_f32_16x16x32_bf16(al[fr], wh[fc], acc[fr][fc], 0, 0, 0);
            }
    }
}

// chunk state: S(p,n) = sum_s exp(la63-la[s]) dt[s] x[s][p] B[s][n]  -> hloc[tile]
// 2-term: A = xT pairs, W = (w*B) single bf16
__global__ __launch_bounds__(256)
void chunk_state_kernel(const u16* __restrict__ xTh, const u16* __restrict__ xTl,
                        const u16* __restrict__ bch, const u16* __restrict__ bcl,
                        const float* __restrict__ la, const float* __restrict__ dtb,
                        float* __restrict__ hloc)
{
    __shared__ alignas(16) u16 lA[2 * 4096];
    __shared__ alignas(16) u16 lW[4096];
    __shared__ float la_sh[64], w_sh[64];
    const int bh = blockIdx.x, c = blockIdx.y;
    const int b = bh / NHEADS, h = bh - b * NHEADS;
    const int row0 = b * SEQLEN + c * Q;
    const size_t tile = (size_t)(bh * NCHUNK + c);
    const int tid = threadIdx.x;

    if (tid < 64) la_sh[tid] = la[(size_t)(row0 + tid) * NHEADS + h];
    __syncthreads();
    if (tid < 64)
        w_sh[tid] = expf(la_sh[63] - la_sh[tid]) * dtb[(size_t)(row0 + tid) * NHEADS + h];
    {
        const int kh = tid & 7, rr = tid >> 3;
        #pragma unroll
        for (int cc = 0; cc < 2; cc++) {
            int row = rr + cc * 32;
            int lws = kh * 512 + ((row & 0x38) | ((row ^ kh) & 7)) * 8;
            *(u16x8*)(lA + lws)        = *(const u16x8*)(xTh + tile * 4096 + row * 64 + kh * 8);
            *(u16x8*)(lA + 4096 + lws) = *(const u16x8*)(xTl + tile * 4096 + row * 64 + kh * 8);
        }
    }
    __syncthreads();
    {
        const int n = tid & 63, sg = tid >> 6;
        #pragma unroll
        for (int i = 0; i < 16; i++) {
            int s = sg + i * 4;
            size_t gidx = (size_t)(row0 + s) * 128 + n;
            float bv = bf2f(bch[gidx]) + bf2f(bcl[gidx]);
            float v = bv * w_sh[s];
            int addr = (s >> 3) * 512 + ((n & 0x38) | ((n ^ (s >> 3)) & 7)) * 8 + (s & 7);
            lW[addr] = f2bf(v);
        }
    }
    __syncthreads();
    const int lane = tid & 63, wid = tid >> 6;
    const int wm = wid >> 1, wn = wid & 1;
    const int l15 = lane & 15, lq = lane >> 4;
    f32x4 acc[2][2];
    const f32x4 z4 = {0.f, 0.f, 0.f, 0.f};
    acc[0][0] = z4; acc[0][1] = z4; acc[1][0] = z4; acc[1][1] = z4;
    gemm2(lA, lW, wm * 32 + l15, wn * 32 + l15, lq, acc);
    #pragma unroll
    for (int fr = 0; fr < 2; fr++)
        #pragma unroll
        for (int fc = 0; fc < 2; fc++)
            #pragma unroll
            for (int r = 0; r < 4; r++) {
                int p = wm * 32 + fr * 16 + lq * 4 + r;
                int n = wn * 32 + fc * 16 + l15;
                hloc[tile * 4096 + p * 64 + n] = acc[fr][fc][r];
            }
}

// in-place sequential fold: hloc[c] := state ENTERING chunk c
// grid (96 bh, 16 p-slices) x 256 threads
__global__ __launch_bounds__(256)
void combine_kernel(float* __restrict__ hloc, const float* __restrict__ la)
{
    const int bh = blockIdx.x;
    const int b = bh / NHEADS, h = bh - b * NHEADS;
    const int off = blockIdx.y * 256 + threadIdx.x;
    float run = 0.f;
    for (int c = 0; c < NCHUNK; c++) {
        float* ptr = hloc + ((size_t)(bh * NCHUNK + c)) * 4096 + off;
        float sv = *ptr;
        *ptr = run;
        float cd = expf(la[(size_t)(b * SEQLEN + c * Q + Q - 1) * NHEADS + h]);
        run = fmaf(run, cd, sv);
    }
}

// chunk y + fused gate/norm_w/sqsum, 2-term gemms; ygp stored SINGLE bf16
__global__ __launch_bounds__(256)
void chunk_y_kernel(const u16* __restrict__ xTh, const u16* __restrict__ xTl,
                    const u16* __restrict__ bch, const u16* __restrict__ bcl,
                    const float* __restrict__ hloc, const float* __restrict__ la,
                    const float* __restrict__ dtb, const float* __restrict__ Dp,
                    const float* __restrict__ z, const float* __restrict__ norm_w,
                    u16* __restrict__ ygp, float* __restrict__ sqsum)
{
    __shared__ alignas(16) u16 r1[2 * 4096];   // C pairs -> P pairs
    __shared__ alignas(16) u16 r2[4096];       // hin -> B -> x (all single)
    __shared__ float la_sh[64], dt_sh[64], ssh[64];
    const int bh = blockIdx.x, c = blockIdx.y;
    const int b = bh / NHEADS, h = bh - b * NHEADS;
    const int row0 = b * SEQLEN + c * Q;
    const size_t tile = (size_t)(bh * NCHUNK + c);
    const int tid = threadIdx.x;
    if (tid < 64) {
        la_sh[tid] = la[(size_t)(row0 + tid) * NHEADS + h];
        dt_sh[tid] = dtb[(size_t)(row0 + tid) * NHEADS + h];
        ssh[tid] = 0.f;
    }
    const int kh = tid & 7, rr = tid >> 3;
    #pragma unroll
    for (int cc = 0; cc < 2; cc++) {
        int row = rr + cc * 32;
        int lws = kh * 512 + ((row & 0x38) | ((row ^ kh) & 7)) * 8;
        *(u16x8*)(r1 + lws)        = *(const u16x8*)(bch + (size_t)(row0 + row) * 128 + 64 + kh * 8);
        *(u16x8*)(r1 + 4096 + lws) = *(const u16x8*)(bcl + (size_t)(row0 + row) * 128 + 64 + kh * 8);
        float4 f0 = *(const float4*)(hloc + tile * 4096 + row * 64 + kh * 8);
        float4 f1 = *(const float4*)(hloc + tile * 4096 + row * 64 + kh * 8 + 4);
        float vals[8] = {f0.x, f0.y, f0.z, f0.w, f1.x, f1.y, f1.z, f1.w};
        u16x8 hh;
        #pragma unroll
        for (int j = 0; j < 8; j++) hh[j] = f2bf(vals[j]);
        *(u16x8*)(r2 + lws) = hh;
    }
    __syncthreads();
    const int lane = tid & 63, wid = tid >> 6;
    const int wm = wid >> 1, wn = wid & 1;
    const int l15 = lane & 15, lq = lane >> 4;
    const int ar0 = wm * 32 + l15, wr0 = wn * 32 + l15;
    const f32x4 z4 = {0.f, 0.f, 0.f, 0.f};
    f32x4 acc2[2][2];
    acc2[0][0] = z4; acc2[0][1] = z4; acc2[1][0] = z4; acc2[1][1] = z4;
    gemm2(r1, r2, ar0, wr0, lq, acc2);
    __syncthreads();
    #pragma unroll
    for (int cc = 0; cc < 2; cc++) {
        int row = rr + cc * 32;
        int lws = kh * 512 + ((row & 0x38) | ((row ^ kh) & 7)) * 8;
        *(u16x8*)(r2 + lws) = *(const u16x8*)(bch + (size_t)(row0 + row) * 128 + kh * 8);
    }
    __syncthreads();
    f32x4 accG[2][2];
    accG[0][0] = z4; accG[0][1] = z4; accG[1][0] = z4; accG[1][1] = z4;
    gemm2(r1, r2, ar0, wr0, lq, accG);
    __syncthreads();
    const float Dph = Dp[h];
    #pragma unroll
    for (int fr = 0; fr < 2; fr++)
        #pragma unroll
        for (int fc = 0; fc < 2; fc++)
            #pragma unroll
            for (int r = 0; r < 4; r++) {
                int t = wm * 32 + fr * 16 + lq * 4 + r;
                int s = wn * 32 + fc * 16 + l15;
                float v = 0.f;
                if (s <= t) v = accG[fr][fc][r] * expf(la_sh[t] - la_sh[s]) * dt_sh[s];
                if (s == t) v += Dph;
                u16 hh = f2bf(v), ll = f2bf(v - bf2f(hh));
                int addr = (s >> 3) * 512 + ((t & 0x38) | ((t ^ (s >> 3)) & 7)) * 8 + (s & 7);
                r1[addr] = hh;
                r1[4096 + addr] = ll;
            }
    #pragma unroll
    for (int cc = 0; cc < 2; cc++) {
        int row = rr + cc * 32;
        int lws = kh * 512 + ((row & 0x38) | ((row ^ kh) & 7)) * 8;
        *(u16x8*)(r2 + lws) = *(const u16x8*)(xTh + tile * 4096 + row * 64 + kh * 8);
    }
    __syncthreads();
    f32x4 acc1[2][2];
    acc1[0][0] = z4; acc1[0][1] = z4; acc1[1][0] = z4; acc1[1][1] = z4;
    gemm2(r1, r2, ar0, wr0, lq, acc1);
    // fused epilogue: gate + norm_w + single-bf16 store + sqsum
    #pragma unroll
    for (int fr = 0; fr < 2; fr++)
        #pragma unroll
        for (int r = 0; r < 4; r++) {
            int t = wm * 32 + fr * 16 + lq * 4 + r;
            size_t row = row0 + t;
            float Et = expf(la_sh[t]);
            float s2 = 0.f;
            #pragma unroll
            for (int fc = 0; fc < 2; fc++) {
                int hp = h * 64 + wn * 32 + fc * 16 + l15;
                float yv = acc1[fr][fc][r] + Et * acc2[fr][fc][r];
                float zv = z[row * D_INNER + hp];
                float gv = yv * (zv / (1.f + expf(-zv)));
                s2 = fmaf(gv, gv, s2);
                float gn = gv * norm_w[hp];
                ygp[row * D_INNER + hp] = f2bf(gn);
            }
            s2 += __shfl_xor(s2, 1);
            s2 += __shfl_xor(s2, 2);
            s2 += __shfl_xor(s2, 4);
            s2 += __shfl_xor(s2, 8);
            if (l15 == 0) atomicAdd(&ssh[t], s2);
        }
    __syncthreads();
    if (tid < 64) atomicAdd(&sqsum[row0 + tid], ssh[tid]);
}

__global__ __launch_bounds__(256)
void layernorm_kernel(const float* __restrict__ r, const float* __restrict__ gam,
                      const float* __restrict__ bet, float* __restrict__ out)
{
    const int row = blockIdx.x;
    const float* rr = r + (size_t)row * D_MODEL;
    const int tid = threadIdx.x;
    float v[3];
    float s = 0.f, s2 = 0.f;
    #pragma unroll
    for (int i = 0; i < 3; i++) {
        v[i] = rr[tid + i * 256];
        s += v[i];
        s2 = fmaf(v[i], v[i], s2);
    }
    #pragma unroll
    for (int o = 32; o > 0; o >>= 1) { s += __shfl_xor(s, o); s2 += __shfl_xor(s2, o); }
    __shared__ float rs[4], rs2[4];
    if ((tid & 63) == 0) { rs[tid >> 6] = s; rs2[tid >> 6] = s2; }
    __syncthreads();
    float S  = rs[0] + rs[1] + rs[2] + rs[3];
    float S2 = rs2[0] + rs2[1] + rs2[2] + rs2[3];
    float mu  = S * (1.f / D_MODEL);
    float var = S2 * (1.f / D_MODEL) - mu * mu;
    float inv = rsqrtf(var + 1e-5f);
    #pragma unroll
    for (int i = 0; i < 3; i++) {
        int e = tid + i * 256;
        out[(size_t)row * D_MODEL + e] = (v[i] - mu) * inv * gam[e] + bet[e];
    }
}

extern "C" void kernel_launch(void* const* d_in, const int* in_sizes, int n_in,
                              void* d_out, int out_size, void* d_ws, size_t ws_size,
                              hipStream_t stream)
{
    const float* x        = (const float*)d_in[0];
    const int*   lengths  = (const int*)d_in[1];
    const float* in_w[2]    = {(const float*)d_in[2],  (const float*)d_in[10]};
    const float* conv_w[2]  = {(const float*)d_in[3],  (const float*)d_in[11]};
    const float* conv_b[2]  = {(const float*)d_in[4],  (const float*)d_in[12]};
    const float* dt_bias[2] = {(const float*)d_in[5],  (const float*)d_in[13]};
    const float* A_log[2]   = {(const float*)d_in[6],  (const float*)d_in[14]};
    const float* Dp[2]      = {(const float*)d_in[7],  (const float*)d_in[15]};
    const float* norm_w[2]  = {(const float*)d_in[8],  (const float*)d_in[16]};
    const float* out_w[2]   = {(const float*)d_in[9],  (const float*)d_in[17]};
    const float* op_w = (const float*)d_in[18];
    const float* op_b = (const float*)d_in[19];
    const float* ln_g = (const float*)d_in[20];
    const float* ln_b = (const float*)d_in[21];
    float* outp = (float*)d_out;

    // ---- workspace layout (same 262.4 MB footprint) ----
    float* z    = (float*)d_ws;                               // R0: 8192*1536
    float* xbcr = z + (size_t)NROWS * D_INNER;                // R1: 8192*1664 (-> hloc)
    float* la   = xbcr + (size_t)NROWS * CONV_DIM;            // R2a
    float* dtb  = la  + (size_t)NROWS * NHEADS;               // R2b
    float* sqs  = dtb + (size_t)NROWS * NHEADS;               // R2c: 8192 f32 (sqsum)
    u16*  xTh   = (u16*)(sqs + (size_t)NROWS * NHEADS);       // R3
    u16*  xTl   = xTh + (size_t)NROWS * D_INNER;
    u16*  bch   = xTl + (size_t)NROWS * D_INNER;
    u16*  bcl   = bch + (size_t)NROWS * 128;
    float* ybuf = (float*)(bcl + (size_t)NROWS * 128);        // R4
    u16*  R5    = (u16*)(ybuf + (size_t)NROWS * D_INNER);     // R5

    float* hloc  = xbcr;          // after conv, xbcr dead -> chunk states

    // R5: persistent x single bf16 + final residual
    u16*  xq   = R5;
    float* rbuf = (float*)(R5 + (size_t)NROWS * D_MODEL);

    // per-dir transient: in_w single bf16 in R4 (dead until chunk_y)
    u16* iw   = (u16*)ybuf;
    u16* yg_p = (u16*)ybuf;       // single bf16, rows of 1536

    // per-dir out-proj prep in R3 (dead after chunk_y)
    u16* oph  = xTh;
    u16* owTh = oph  + (size_t)D_MODEL * D_INNER;
    u16* wdp  = owTh + (size_t)D_MODEL * D_INNER;   // 768 x 1536 single bf16

    size_t need = ((size_t)NROWS * (D_INNER + CONV_DIM + 3*NHEADS + CONV_DIM +
                                    D_INNER + D_INNER)) * sizeof(float);
    if (ws_size < need) return;

    // x single bf16 once (flip handled by GEMM row indexing)
    convert_single_kernel<<<(NROWS*D_MODEL/4 + 255)/256, 256, 0, stream>>>(
        x, xq, NROWS*D_MODEL/4);

    for (int dir = 0; dir < 2; dir++) {
        // 0. convert in_w single bf16 (R4)
        convert_single_kernel<<<(D_IN_PROJ*D_MODEL/4 + 255)/256, 256, 0, stream>>>(
            in_w[dir], iw, D_IN_PROJ*D_MODEL/4);
        // 1. in_proj (split outputs): [z | xbcr], dt cols skipped
        mfma_gemm<<<dim3(26, 64), 256, 0, stream>>>(
            xq, D_MODEL, iw, D_MODEL, D_IN_PROJ, D_MODEL,
            lengths, dir, 0, 1,
            nullptr, 0, z, xbcr, nullptr, nullptr, nullptr, nullptr);
        // 1b. exact fp32 dt_raw -> la
        dt_exact_kernel<<<NROWS/4, 256, 0, stream>>>(
            x, in_w[dir] + (size_t)(D_INNER + CONV_DIM) * D_MODEL, lengths, dir, la);
        // 2. conv + silu + transpose + dt/cumsum
        conv_silu_fused_kernel<<<dim3(27, BATCH*NCHUNK), 256, 0, stream>>>(
            xbcr, conv_w[dir], conv_b[dir], xTh, xTl, bch, bcl,
            dt_bias[dir], A_log[dir], dtb, la);
        // 3. chunked SSD scan
        chunk_state_kernel<<<dim3(BATCH*NHEADS, NCHUNK), 256, 0, stream>>>(
            xTh, xTl, bch, bcl, la, dtb, hloc);
        combine_kernel<<<dim3(BATCH*NHEADS, 16), 256, 0, stream>>>(hloc, la);
        // 4. chunk_y with fused gate + norm_w + sqsum (single bf16 -> yg_p)
        hipMemsetAsync(sqs, 0, NROWS * sizeof(float), stream);
        chunk_y_kernel<<<dim3(BATCH*NHEADS, NCHUNK), 256, 0, stream>>>(
            xTh, xTl, bch, bcl, hloc, la, dtb, Dp[dir],
            z, norm_w[dir], yg_p, sqs);
        // 5. fused output projection: Wd = op_w[:, dir*768:+768] @ out_w
        prep_outw_kernel<<<NCONV_BLK + NT_BLK, 256, 0, stream>>>(
            op_w, out_w[dir], oph, owTh);
        mfma_gemm<<<dim3(12, 6), 256, 0, stream>>>(
            oph + dir * D_MODEL, 2*D_MODEL, owTh, D_MODEL, D_INNER, D_MODEL,
            lengths, 0, 0, 4,
            nullptr, D_INNER, nullptr, nullptr, wdp, nullptr, nullptr, nullptr);
        // 6. big out-GEMM with RMS scale: fwd writes rbuf, bwd adds flipped
        if (dir == 0) {
            mfma_gemm<<<dim3(6, 64), 256, 0, stream>>>(
                yg_p, D_INNER, wdp, D_INNER, D_MODEL, D_INNER,
                lengths, 0, 0, 0,
                rbuf, D_MODEL, nullptr, nullptr, nullptr, op_b, x, sqs);
        } else {
            mfma_gemm<<<dim3(6, 64), 256, 0, stream>>>(
                yg_p, D_INNER, wdp, D_INNER, D_MODEL, D_INNER,
                lengths, 0, 1, 3,
                rbuf, D_MODEL, nullptr, nullptr, nullptr, nullptr, nullptr, sqs);
        }
    }

    // layernorm -> out
    layernorm_kernel<<<NROWS, 256, 0, stream>>>(rbuf, ln_g, ln_b, outp);
}

// Round 21
// 583.121 us; speedup vs baseline: 1.3380x; 1.0586x over previous
//
#include <hip/hip_runtime.h>
#include <cstdint>
#include <cstddef>

#define D_MODEL   768
#define D_STATE   64
#define D_INNER   1536
#define HEADDIM   64
#define NHEADS    24
#define D_CONV    4
#define CONV_DIM  1664      // D_INNER + 2*D_STATE
#define D_IN_PROJ 3224      // 2*D_INNER + 2*D_STATE + NHEADS
#define BATCH     4
#define SEQLEN    2048
#define NROWS     (BATCH*SEQLEN)   // 8192
#define NCHUNK    32
#define Q         64               // chunk length

typedef unsigned short u16;
typedef __attribute__((ext_vector_type(8))) short bf16x8;
typedef __attribute__((ext_vector_type(8))) unsigned short u16x8;
typedef __attribute__((ext_vector_type(4))) float f32x4;

__device__ __forceinline__ int flip_row(int m, const int* __restrict__ lengths) {
    int b = m >> 11;
    int t = m & (SEQLEN - 1);
    int len = lengths[b];
    int ft = (t < len) ? (len - 1 - t) : t;
    return (b << 11) | ft;
}

__device__ __forceinline__ u16 f2bf(float f) {
    unsigned int u = __float_as_uint(f);
    unsigned int r = u + 0x7FFFu + ((u >> 16) & 1u);
    return (u16)(r >> 16);
}
__device__ __forceinline__ float bf2f(u16 h) {
    return __uint_as_float(((unsigned int)h) << 16);
}

// f32 -> single bf16 array
__global__ __launch_bounds__(256)
void convert_single_kernel(const float* __restrict__ in, u16* __restrict__ hi, int n4)
{
    int i = blockIdx.x * 256 + threadIdx.x;
    if (i >= n4) return;
    float4 v = *(const float4*)(in + (size_t)i * 4);
    ushort4 h;
    h.x = f2bf(v.x); h.y = f2bf(v.y); h.z = f2bf(v.z); h.w = f2bf(v.w);
    *(ushort4*)(hi + (size_t)i * 4) = h;
}

// prep for fused output projection: (a) op_w (768x1536) -> single bf16,
// (b) transpose out_w (768x1536) -> owT[1536][768] single bf16
#define NCONV_BLK 1152    // 768*1536/4/256
#define NT_BLK    288     // 24 x 12 transpose tiles
__global__ __launch_bounds__(256)
void prep_outw_kernel(const float* __restrict__ op_w, const float* __restrict__ ow,
                      u16* __restrict__ oph, u16* __restrict__ owTh)
{
    const int bid = blockIdx.x;
    const int tid = threadIdx.x;
    if (bid < NCONV_BLK) {
        int i = bid * 256 + tid;
        float4 v = *(const float4*)(op_w + (size_t)i * 4);
        ushort4 h;
        h.x = f2bf(v.x); h.y = f2bf(v.y); h.z = f2bf(v.z); h.w = f2bf(v.w);
        *(ushort4*)(oph + (size_t)i * 4) = h;
        return;
    }
    __shared__ float T[64][65];
    const int tb = bid - NCONV_BLK;
    const int e0 = (tb % 24) * 64;
    const int d0 = (tb / 24) * 64;
    const int col = tid & 63, rg = tid >> 6;
    #pragma unroll
    for (int i = 0; i < 16; i++) {
        int r = rg + i * 4;
        T[r][col] = ow[(size_t)(d0 + r) * D_INNER + e0 + col];
    }
    __syncthreads();
    const int er = tid >> 2, dc0 = (tid & 3) * 16;
    u16x8 ph[2];
    #pragma unroll
    for (int j = 0; j < 16; j++)
        ph[j >> 3][j & 7] = f2bf(T[dc0 + j][er]);
    size_t obase = (size_t)(e0 + er) * D_MODEL + d0 + dc0;
    *(u16x8*)(owTh + obase)     = ph[0];
    *(u16x8*)(owTh + obase + 8) = ph[1];
}

// ---------- single-bf16 MFMA GEMM, BK=32, DOUBLE-BUFFERED LDS ----------
// 128x128 tile, 256 threads = 4 waves (2x2), 4x4 16x16 frags/wave.
// mode 0: C f32 = scale*acc + bias[n] + resid[m]       (scale from sqsum)
// mode 1: split store BF16 -> Cz16 | Cxbc16 (dt columns handled by dt_exact)
// mode 3: C[crow*ldc+n] += scale*acc (sequential launches only)
// mode 4: Cp[crow*ldc+n] = bf16(acc)
__global__ __launch_bounds__(256, 4)
void mfma_gemm(const u16* __restrict__ A, int lda,
               const u16* __restrict__ W, int ldw,
               int N, int K, const int* __restrict__ lengths,
               int flipA, int flipC, int mode,
               float* __restrict__ C, int ldc,
               u16* __restrict__ Cz16, u16* __restrict__ Cxbc16,
               u16* __restrict__ Cp,
               const float* __restrict__ bias, const float* __restrict__ resid,
               const float* __restrict__ sqsum)
{
    __shared__ alignas(16) u16 lds[2 * 2 * 4096];   // [buf][matrix][4096]
    const int tid = threadIdx.x;
    const int m0 = blockIdx.y * 128;
    const int n0 = blockIdx.x * 128;
    const int lane = tid & 63;
    const int wid = tid >> 6;
    const int wm = wid >> 1, wn = wid & 1;

    const int kh = tid & 3;           // k-group (8 u16 each), 0..3
    const int rb = tid >> 2;          // 0..63
    int aoff[2], woff[2], lws[2];
    #pragma unroll
    for (int c = 0; c < 2; c++) {
        int row = rb + c * 64;
        int grow = m0 + row;
        if (flipA) grow = flip_row(grow, lengths);
        aoff[c] = grow * lda + kh * 8;
        int wrow = n0 + row; if (wrow >= N) wrow = N - 1;
        woff[c] = wrow * ldw + kh * 8;
        lws[c] = kh * 1024 + ((row & 0x78) | ((row ^ (kh << 1)) & 7)) * 8;
    }

    f32x4 acc[4][4];
    const f32x4 zero4 = {0.f, 0.f, 0.f, 0.f};
    #pragma unroll
    for (int i = 0; i < 4; i++)
        #pragma unroll
        for (int j = 0; j < 4; j++) acc[i][j] = zero4;

    const int l15 = lane & 15, lq = lane >> 4;
    const int arow0 = wm * 64 + l15;
    const int wrow0 = wn * 64 + l15;
    const int abase = lq * 1024 + ((arow0 & 0x78) | ((arow0 ^ (lq << 1)) & 7)) * 8;
    const int wbase = lq * 1024 + ((wrow0 & 0x78) | ((wrow0 ^ (lq << 1)) & 7)) * 8;

    // prologue: tile 0 -> buf0 ; prefetch tile 1 into regs
    u16x8 va[2], vc[2];
    #pragma unroll
    for (int c = 0; c < 2; c++) {
        va[c] = *(const u16x8*)(A + (size_t)aoff[c]);
        vc[c] = *(const u16x8*)(W + (size_t)woff[c]);
    }
    #pragma unroll
    for (int c = 0; c < 2; c++) {
        *(u16x8*)(lds + 0 * 4096 + lws[c]) = va[c];
        *(u16x8*)(lds + 1 * 4096 + lws[c]) = vc[c];
    }
    if (K > 32) {
        #pragma unroll
        for (int c = 0; c < 2; c++) {
            va[c] = *(const u16x8*)(A + (size_t)aoff[c] + 32);
            vc[c] = *(const u16x8*)(W + (size_t)woff[c] + 32);
        }
    }
    __syncthreads();

    int cur = 0;
    for (int kt = 0; kt < K; kt += 32) {
        u16* Lc = lds + cur * 8192;
        if (kt + 32 < K) {
            u16* Ln = lds + (cur ^ 1) * 8192;
            #pragma unroll
            for (int c = 0; c < 2; c++) {           // stage tile k+1 -> other buf
                *(u16x8*)(Ln + 0 * 4096 + lws[c]) = va[c];
                *(u16x8*)(Ln + 1 * 4096 + lws[c]) = vc[c];
            }
            if (kt + 64 < K) {                      // prefetch tile k+2
                #pragma unroll
                for (int c = 0; c < 2; c++) {
                    va[c] = *(const u16x8*)(A + (size_t)aoff[c] + kt + 64);
                    vc[c] = *(const u16x8*)(W + (size_t)woff[c] + kt + 64);
                }
            }
        }
        bf16x8 ah[4], wv[4];
        #pragma unroll
        for (int f = 0; f < 4; f++) {
            ah[f] = *(const bf16x8*)(Lc + 0 * 4096 + abase + f * 128);
            wv[f] = *(const bf16x8*)(Lc + 1 * 4096 + wbase + f * 128);
        }
        #pragma unroll
        for (int fr = 0; fr < 4; fr++)
            #pragma unroll
            for (int fc = 0; fc < 4; fc++)
                acc[fr][fc] = __builtin_amdgcn_mfma_f32_16x16x32_bf16(
                    ah[fr], wv[fc], acc[fr][fc], 0, 0, 0);
        __syncthreads();                            // single barrier per K-step
        cur ^= 1;
    }

    #pragma unroll
    for (int fr = 0; fr < 4; fr++) {
        int mr[4], crow[4];
        float scl[4];
        #pragma unroll
        for (int r = 0; r < 4; r++) {
            mr[r] = m0 + wm * 64 + fr * 16 + lq * 4 + r;
            crow[r] = flipC ? flip_row(mr[r], lengths) : mr[r];
            scl[r] = sqsum ? rsqrtf(sqsum[mr[r]] * (1.f / D_INNER) + 1e-5f) : 1.f;
        }
        #pragma unroll
        for (int fc = 0; fc < 4; fc++) {
            const int nb = n0 + wn * 64 + fc * 16;
            const int nn = nb + l15;
            if (nn >= N) continue;
            #pragma unroll
            for (int r = 0; r < 4; r++) {
                float v = acc[fr][fc][r];
                if (mode == 1) {
                    if (nb < D_INNER)
                        Cz16[(size_t)crow[r] * D_INNER + nn] = f2bf(v);
                    else if (nb < D_INNER + CONV_DIM)
                        Cxbc16[(size_t)crow[r] * CONV_DIM + (nn - D_INNER)] = f2bf(v);
                    // dt columns handled exactly by dt_exact_kernel
                } else if (mode == 3) {
                    C[(size_t)crow[r] * ldc + nn] += v * scl[r];
                } else if (mode == 4) {
                    Cp[(size_t)crow[r] * ldc + nn] = f2bf(v);
                } else {
                    v = v * scl[r] + bias[nn] + resid[(size_t)mr[r] * D_MODEL + nn];
                    C[(size_t)crow[r] * ldc + nn] = v;
                }
            }
        }
    }
}

// exact fp32 dt_raw: la[row][h] = dot(x[fliprow], in_w[3200+h])  (24 heads)
__global__ __launch_bounds__(256)
void dt_exact_kernel(const float* __restrict__ x, const float* __restrict__ wdt,
                     const int* __restrict__ lengths, int flipA,
                     float* __restrict__ la)
{
    const int wv = threadIdx.x >> 6, lane = threadIdx.x & 63;
    const int row = blockIdx.x * 4 + wv;
    int grow = flipA ? flip_row(row, lengths) : row;
    const float* xr = x + (size_t)grow * D_MODEL;
    float xv[12];
    #pragma unroll
    for (int k = 0; k < 12; k++) xv[k] = xr[k * 64 + lane];
    for (int c = 0; c < NHEADS; c++) {
        const float* wr = wdt + (size_t)c * D_MODEL;
        float acc = 0.f;
        #pragma unroll
        for (int k = 0; k < 12; k++) acc = fmaf(xv[k], wr[k * 64 + lane], acc);
        #pragma unroll
        for (int o = 32; o > 0; o >>= 1) acc += __shfl_xor(acc, o);
        if (lane == 0) la[(size_t)row * NHEADS + c] = acc;
    }
}

// fused causal conv + silu + per-chunk transpose + (cg==26) dt/cumsum
// xbcr is bf16; outputs: xT single [tile][p][s], bc single [row][128]
__global__ __launch_bounds__(256)
void conv_silu_fused_kernel(const u16* __restrict__ xbcr, const float* __restrict__ cw,
                            const float* __restrict__ cb,
                            u16* __restrict__ xT, u16* __restrict__ bc,
                            const float* __restrict__ dt_bias, const float* __restrict__ A_log,
                            float* __restrict__ dtb, float* __restrict__ la)
{
    __shared__ float T[64][65];
    const int cg = blockIdx.x;
    const int rc = blockIdx.y;
    const int tid = threadIdx.x;
    if (cg == 26) {
        const int lane2 = tid & 63, w = tid >> 6;
        const int row0 = rc * 64;
        #pragma unroll
        for (int i = 0; i < 6; i++) {
            int h = w * 6 + i;
            size_t idx = (size_t)(row0 + lane2) * NHEADS + h;
            float v = la[idx] + dt_bias[h];
            float sp = (v > 20.f) ? v : log1pf(expf(v));
            dtb[idx] = sp;
            float dA = sp * (-expf(A_log[h]));
            #pragma unroll
            for (int o = 1; o < 64; o <<= 1) {
                float u = __shfl_up(dA, o);
                if (lane2 >= o) dA += u;
            }
            la[idx] = dA;
        }
        return;
    }
    const int col = tid & 63, rg = tid >> 6;
    const int c = cg * 64 + col;
    const int rstart = rc * 64 + rg * 16;
    const int t0 = rstart & (SEQLEN - 1);
    const float c0 = cw[c*4+0], c1 = cw[c*4+1], c2 = cw[c*4+2], c3 = cw[c*4+3];
    const float cbv = cb[c];
    const u16* base = xbcr + (size_t)rstart * CONV_DIM + c;
    float w0 = (t0 >= 3) ? bf2f(base[-3 * CONV_DIM]) : 0.f;
    float w1 = (t0 >= 2) ? bf2f(base[-2 * CONV_DIM]) : 0.f;
    float w2 = (t0 >= 1) ? bf2f(base[-1 * CONV_DIM]) : 0.f;
    const bool isx = (cg < 24);
    #pragma unroll
    for (int r = 0; r < 16; r++) {
        float w3 = bf2f(base[r * CONV_DIM]);
        float acc = cbv + w0*c0 + w1*c1 + w2*c2 + w3*c3;
        float val = acc / (1.f + expf(-acc));
        if (isx) {
            T[rg*16 + r][col] = val;
        } else {
            bc[(size_t)(rstart + r) * 128 + (c - D_INNER)] = f2bf(val);
        }
        w0 = w1; w1 = w2; w2 = w3;
    }
    if (!isx) return;
    __syncthreads();
    const int p = tid >> 2, s0 = (tid & 3) * 16;
    size_t tile = (size_t)(((rc >> 5) * NHEADS + cg) * NCHUNK + (rc & 31));
    size_t obase = tile * 4096 + p * 64 + s0;
    u16x8 ph[2];
    #pragma unroll
    for (int j = 0; j < 16; j++)
        ph[j >> 3][j & 7] = f2bf(T[s0 + j][p]);
    *(u16x8*)(xT + obase)     = ph[0];
    *(u16x8*)(xT + obase + 8) = ph[1];
}

// single-bf16 64x64x64 GEMM helper: 1 MFMA per fragment.
__device__ __forceinline__ void gemm1(const u16* rA, const u16* rW,
                                      int ar0, int wr0, int lq, f32x4 acc[2][2])
{
    #pragma unroll
    for (int kk = 0; kk < 2; kk++) {
        const int khs = kk * 4 + lq;
        const int ab = khs * 512 + ((ar0 & 0x38) | ((ar0 ^ khs) & 7)) * 8;
        const int wb = khs * 512 + ((wr0 & 0x38) | ((wr0 ^ khs) & 7)) * 8;
        bf16x8 ah[2], wh[2];
        #pragma unroll
        for (int f = 0; f < 2; f++) {
            ah[f] = *(const bf16x8*)(rA + ab + f * 128);
            wh[f] = *(const bf16x8*)(rW + wb + f * 128);
        }
        #pragma unroll
        for (int fr = 0; fr < 2; fr++)
            #pragma unroll
            for (int fc = 0; fc < 2; fc++)
                acc[fr][fc] = __builtin_amdgcn_mfma_f32_16x16x32_bf16(
                    ah[fr], wh[fc], acc[fr][fc], 0, 0, 0);
    }
}

// chunk state: S(p,n) = sum_s exp(la63-la[s]) dt[s] x[s][p] B[s][n]  -> hloc[tile]
// all single bf16
__global__ __launch_bounds__(256)
void chunk_state_kernel(const u16* __restrict__ xT, const u16* __restrict__ bc,
                        const float* __restrict__ la, const float* __restrict__ dtb,
                        float* __restrict__ hloc)
{
    __shared__ alignas(16) u16 lA[4096];
    __shared__ alignas(16) u16 lW[4096];
    __shared__ float la_sh[64], w_sh[64];
    const int bh = blockIdx.x, c = blockIdx.y;
    const int b = bh / NHEADS, h = bh - b * NHEADS;
    const int row0 = b * SEQLEN + c * Q;
    const size_t tile = (size_t)(bh * NCHUNK + c);
    const int tid = threadIdx.x;

    if (tid < 64) la_sh[tid] = la[(size_t)(row0 + tid) * NHEADS + h];
    __syncthreads();
    if (tid < 64)
        w_sh[tid] = expf(la_sh[63] - la_sh[tid]) * dtb[(size_t)(row0 + tid) * NHEADS + h];
    {
        const int kh = tid & 7, rr = tid >> 3;
        #pragma unroll
        for (int cc = 0; cc < 2; cc++) {
            int row = rr + cc * 32;
            int lws = kh * 512 + ((row & 0x38) | ((row ^ kh) & 7)) * 8;
            *(u16x8*)(lA + lws) = *(const u16x8*)(xT + tile * 4096 + row * 64 + kh * 8);
        }
    }
    __syncthreads();
    {
        const int n = tid & 63, sg = tid >> 6;
        #pragma unroll
        for (int i = 0; i < 16; i++) {
            int s = sg + i * 4;
            float bv = bf2f(bc[(size_t)(row0 + s) * 128 + n]);
            float v = bv * w_sh[s];
            int addr = (s >> 3) * 512 + ((n & 0x38) | ((n ^ (s >> 3)) & 7)) * 8 + (s & 7);
            lW[addr] = f2bf(v);
        }
    }
    __syncthreads();
    const int lane = tid & 63, wid = tid >> 6;
    const int wm = wid >> 1, wn = wid & 1;
    const int l15 = lane & 15, lq = lane >> 4;
    f32x4 acc[2][2];
    const f32x4 z4 = {0.f, 0.f, 0.f, 0.f};
    acc[0][0] = z4; acc[0][1] = z4; acc[1][0] = z4; acc[1][1] = z4;
    gemm1(lA, lW, wm * 32 + l15, wn * 32 + l15, lq, acc);
    #pragma unroll
    for (int fr = 0; fr < 2; fr++)
        #pragma unroll
        for (int fc = 0; fc < 2; fc++)
            #pragma unroll
            for (int r = 0; r < 4; r++) {
                int p = wm * 32 + fr * 16 + lq * 4 + r;
                int n = wn * 32 + fc * 16 + l15;
                hloc[tile * 4096 + p * 64 + n] = acc[fr][fc][r];
            }
}

// in-place sequential fold: hloc[c] := state ENTERING chunk c
// grid (96 bh, 16 p-slices) x 256 threads
__global__ __launch_bounds__(256)
void combine_kernel(float* __restrict__ hloc, const float* __restrict__ la)
{
    const int bh = blockIdx.x;
    const int b = bh / NHEADS, h = bh - b * NHEADS;
    const int off = blockIdx.y * 256 + threadIdx.x;
    float run = 0.f;
    for (int c = 0; c < NCHUNK; c++) {
        float* ptr = hloc + ((size_t)(bh * NCHUNK + c)) * 4096 + off;
        float sv = *ptr;
        *ptr = run;
        float cd = expf(la[(size_t)(b * SEQLEN + c * Q + Q - 1) * NHEADS + h]);
        run = fmaf(run, cd, sv);
    }
}

// chunk y + fused gate/norm_w/sqsum, all single-bf16 gemms; z is bf16
__global__ __launch_bounds__(256)
void chunk_y_kernel(const u16* __restrict__ xT, const u16* __restrict__ bc,
                    const float* __restrict__ hloc, const float* __restrict__ la,
                    const float* __restrict__ dtb, const float* __restrict__ Dp,
                    const u16* __restrict__ z16, const float* __restrict__ norm_w,
                    u16* __restrict__ ygp, float* __restrict__ sqsum)
{
    __shared__ alignas(16) u16 r1[4096];   // C -> P (single)
    __shared__ alignas(16) u16 r2[4096];   // hin -> B -> x (single)
    __shared__ float la_sh[64], dt_sh[64], ssh[64];
    const int bh = blockIdx.x, c = blockIdx.y;
    const int b = bh / NHEADS, h = bh - b * NHEADS;
    const int row0 = b * SEQLEN + c * Q;
    const size_t tile = (size_t)(bh * NCHUNK + c);
    const int tid = threadIdx.x;
    if (tid < 64) {
        la_sh[tid] = la[(size_t)(row0 + tid) * NHEADS + h];
        dt_sh[tid] = dtb[(size_t)(row0 + tid) * NHEADS + h];
        ssh[tid] = 0.f;
    }
    const int kh = tid & 7, rr = tid >> 3;
    #pragma unroll
    for (int cc = 0; cc < 2; cc++) {
        int row = rr + cc * 32;
        int lws = kh * 512 + ((row & 0x38) | ((row ^ kh) & 7)) * 8;
        *(u16x8*)(r1 + lws) = *(const u16x8*)(bc + (size_t)(row0 + row) * 128 + 64 + kh * 8);
        float4 f0 = *(const float4*)(hloc + tile * 4096 + row * 64 + kh * 8);
        float4 f1 = *(const float4*)(hloc + tile * 4096 + row * 64 + kh * 8 + 4);
        float vals[8] = {f0.x, f0.y, f0.z, f0.w, f1.x, f1.y, f1.z, f1.w};
        u16x8 hh;
        #pragma unroll
        for (int j = 0; j < 8; j++) hh[j] = f2bf(vals[j]);
        *(u16x8*)(r2 + lws) = hh;
    }
    __syncthreads();
    const int lane = tid & 63, wid = tid >> 6;
    const int wm = wid >> 1, wn = wid & 1;
    const int l15 = lane & 15, lq = lane >> 4;
    const int ar0 = wm * 32 + l15, wr0 = wn * 32 + l15;
    const f32x4 z4 = {0.f, 0.f, 0.f, 0.f};
    f32x4 acc2[2][2];
    acc2[0][0] = z4; acc2[0][1] = z4; acc2[1][0] = z4; acc2[1][1] = z4;
    gemm1(r1, r2, ar0, wr0, lq, acc2);
    __syncthreads();
    #pragma unroll
    for (int cc = 0; cc < 2; cc++) {
        int row = rr + cc * 32;
        int lws = kh * 512 + ((row & 0x38) | ((row ^ kh) & 7)) * 8;
        *(u16x8*)(r2 + lws) = *(const u16x8*)(bc + (size_t)(row0 + row) * 128 + kh * 8);
    }
    __syncthreads();
    f32x4 accG[2][2];
    accG[0][0] = z4; accG[0][1] = z4; accG[1][0] = z4; accG[1][1] = z4;
    gemm1(r1, r2, ar0, wr0, lq, accG);
    __syncthreads();
    const float Dph = Dp[h];
    #pragma unroll
    for (int fr = 0; fr < 2; fr++)
        #pragma unroll
        for (int fc = 0; fc < 2; fc++)
            #pragma unroll
            for (int r = 0; r < 4; r++) {
                int t = wm * 32 + fr * 16 + lq * 4 + r;
                int s = wn * 32 + fc * 16 + l15;
                float v = 0.f;
                if (s <= t) v = accG[fr][fc][r] * expf(la_sh[t] - la_sh[s]) * dt_sh[s];
                if (s == t) v += Dph;
                int addr = (s >> 3) * 512 + ((t & 0x38) | ((t ^ (s >> 3)) & 7)) * 8 + (s & 7);
                r1[addr] = f2bf(v);
            }
    #pragma unroll
    for (int cc = 0; cc < 2; cc++) {
        int row = rr + cc * 32;
        int lws = kh * 512 + ((row & 0x38) | ((row ^ kh) & 7)) * 8;
        *(u16x8*)(r2 + lws) = *(const u16x8*)(xT + tile * 4096 + row * 64 + kh * 8);
    }
    __syncthreads();
    f32x4 acc1[2][2];
    acc1[0][0] = z4; acc1[0][1] = z4; acc1[1][0] = z4; acc1[1][1] = z4;
    gemm1(r1, r2, ar0, wr0, lq, acc1);
    // fused epilogue: gate + norm_w + single-bf16 store + sqsum
    #pragma unroll
    for (int fr = 0; fr < 2; fr++)
        #pragma unroll
        for (int r = 0; r < 4; r++) {
            int t = wm * 32 + fr * 16 + lq * 4 + r;
            size_t row = row0 + t;
            float Et = expf(la_sh[t]);
            float s2 = 0.f;
            #pragma unroll
            for (int fc = 0; fc < 2; fc++) {
                int hp = h * 64 + wn * 32 + fc * 16 + l15;
                float yv = acc1[fr][fc][r] + Et * acc2[fr][fc][r];
                float zv = bf2f(z16[row * D_INNER + hp]);
                float gv = yv * (zv / (1.f + expf(-zv)));
                s2 = fmaf(gv, gv, s2);
                float gn = gv * norm_w[hp];
                ygp[row * D_INNER + hp] = f2bf(gn);
            }
            s2 += __shfl_xor(s2, 1);
            s2 += __shfl_xor(s2, 2);
            s2 += __shfl_xor(s2, 4);
            s2 += __shfl_xor(s2, 8);
            if (l15 == 0) atomicAdd(&ssh[t], s2);
        }
    __syncthreads();
    if (tid < 64) atomicAdd(&sqsum[row0 + tid], ssh[tid]);
}

__global__ __launch_bounds__(256)
void layernorm_kernel(const float* __restrict__ r, const float* __restrict__ gam,
                      const float* __restrict__ bet, float* __restrict__ out)
{
    const int row = blockIdx.x;
    const float* rr = r + (size_t)row * D_MODEL;
    const int tid = threadIdx.x;
    float v[3];
    float s = 0.f, s2 = 0.f;
    #pragma unroll
    for (int i = 0; i < 3; i++) {
        v[i] = rr[tid + i * 256];
        s += v[i];
        s2 = fmaf(v[i], v[i], s2);
    }
    #pragma unroll
    for (int o = 32; o > 0; o >>= 1) { s += __shfl_xor(s, o); s2 += __shfl_xor(s2, o); }
    __shared__ float rs[4], rs2[4];
    if ((tid & 63) == 0) { rs[tid >> 6] = s; rs2[tid >> 6] = s2; }
    __syncthreads();
    float S  = rs[0] + rs[1] + rs[2] + rs[3];
    float S2 = rs2[0] + rs2[1] + rs2[2] + rs2[3];
    float mu  = S * (1.f / D_MODEL);
    float var = S2 * (1.f / D_MODEL) - mu * mu;
    float inv = rsqrtf(var + 1e-5f);
    #pragma unroll
    for (int i = 0; i < 3; i++) {
        int e = tid + i * 256;
        out[(size_t)row * D_MODEL + e] = (v[i] - mu) * inv * gam[e] + bet[e];
    }
}

extern "C" void kernel_launch(void* const* d_in, const int* in_sizes, int n_in,
                              void* d_out, int out_size, void* d_ws, size_t ws_size,
                              hipStream_t stream)
{
    const float* x        = (const float*)d_in[0];
    const int*   lengths  = (const int*)d_in[1];
    const float* in_w[2]    = {(const float*)d_in[2],  (const float*)d_in[10]};
    const float* conv_w[2]  = {(const float*)d_in[3],  (const float*)d_in[11]};
    const float* conv_b[2]  = {(const float*)d_in[4],  (const float*)d_in[12]};
    const float* dt_bias[2] = {(const float*)d_in[5],  (const float*)d_in[13]};
    const float* A_log[2]   = {(const float*)d_in[6],  (const float*)d_in[14]};
    const float* Dp[2]      = {(const float*)d_in[7],  (const float*)d_in[15]};
    const float* norm_w[2]  = {(const float*)d_in[8],  (const float*)d_in[16]};
    const float* out_w[2]   = {(const float*)d_in[9],  (const float*)d_in[17]};
    const float* op_w = (const float*)d_in[18];
    const float* op_b = (const float*)d_in[19];
    const float* ln_g = (const float*)d_in[20];
    const float* ln_b = (const float*)d_in[21];
    float* outp = (float*)d_out;

    // ---- workspace layout (bf16 interchange; hloc DEDICATED region) ----
    u16*  z16   = (u16*)d_ws;                                 // 8192*1536 u16
    u16*  xbcr16= z16 + (size_t)NROWS * D_INNER;              // 8192*1664 u16
    float* la   = (float*)(xbcr16 + (size_t)NROWS * CONV_DIM);
    float* dtb  = la  + (size_t)NROWS * NHEADS;
    float* sqs  = dtb + (size_t)NROWS * NHEADS;               // 8192 f32
    u16*  xT    = (u16*)(sqs + NROWS);                        // 8192*1536 u16
    u16*  bc    = xT + (size_t)NROWS * D_INNER;               // 8192*128 u16
    u16*  R4    = bc + (size_t)NROWS * 128;                   // iw / yg_p (8192*1536 u16)
    u16*  R5    = R4 + (size_t)NROWS * D_INNER;               // xq + rbuf
    u16*  xq    = R5;                                         // 8192*768 u16
    float* rbuf = (float*)(R5 + (size_t)NROWS * D_MODEL);     // 8192*768 f32
    float* hloc = rbuf + (size_t)NROWS * D_MODEL;             // 96*32*4096 f32 (DEDICATED)

    u16*  iw   = R4;                  // in_w single bf16 (dead before chunk_y)
    u16*  yg_p = R4;                  // gated-y single bf16 (rows of 1536)

    // per-dir out-proj prep overlays xT (dead after chunk_y)
    u16* oph  = xT;
    u16* owTh = oph  + (size_t)D_MODEL * D_INNER;
    u16* wdp  = owTh + (size_t)D_MODEL * D_INNER;   // 768 x 1536 single bf16

    size_t need = ((size_t)(hloc + (size_t)BATCH*NHEADS*NCHUNK*4096) - (size_t)d_ws);
    if (ws_size < need) return;

    // x single bf16 once (flip handled by GEMM row indexing)
    convert_single_kernel<<<(NROWS*D_MODEL/4 + 255)/256, 256, 0, stream>>>(
        x, xq, NROWS*D_MODEL/4);

    for (int dir = 0; dir < 2; dir++) {
        // 0. convert in_w single bf16 (R4)
        convert_single_kernel<<<(D_IN_PROJ*D_MODEL/4 + 255)/256, 256, 0, stream>>>(
            in_w[dir], iw, D_IN_PROJ*D_MODEL/4);
        // 1. in_proj (split bf16 outputs): [z16 | xbcr16], dt cols skipped
        mfma_gemm<<<dim3(26, 64), 256, 0, stream>>>(
            xq, D_MODEL, iw, D_MODEL, D_IN_PROJ, D_MODEL,
            lengths, dir, 0, 1,
            nullptr, 0, z16, xbcr16, nullptr, nullptr, nullptr, nullptr);
        // 1b. exact fp32 dt_raw -> la
        dt_exact_kernel<<<NROWS/4, 256, 0, stream>>>(
            x, in_w[dir] + (size_t)(D_INNER + CONV_DIM) * D_MODEL, lengths, dir, la);
        // 2. conv + silu + transpose + dt/cumsum (bf16 in, bf16 out)
        conv_silu_fused_kernel<<<dim3(27, BATCH*NCHUNK), 256, 0, stream>>>(
            xbcr16, conv_w[dir], conv_b[dir], xT, bc,
            dt_bias[dir], A_log[dir], dtb, la);
        // 3. chunked SSD scan (single-bf16 gemms)
        chunk_state_kernel<<<dim3(BATCH*NHEADS, NCHUNK), 256, 0, stream>>>(
            xT, bc, la, dtb, hloc);
        combine_kernel<<<dim3(BATCH*NHEADS, 16), 256, 0, stream>>>(hloc, la);
        // 4. chunk_y with fused gate + norm_w + sqsum (single bf16 -> yg_p)
        hipMemsetAsync(sqs, 0, NROWS * sizeof(float), stream);
        chunk_y_kernel<<<dim3(BATCH*NHEADS, NCHUNK), 256, 0, stream>>>(
            xT, bc, hloc, la, dtb, Dp[dir], z16, norm_w[dir], yg_p, sqs);
        // 5. fused output projection: Wd = op_w[:, dir*768:+768] @ out_w
        prep_outw_kernel<<<NCONV_BLK + NT_BLK, 256, 0, stream>>>(
            op_w, out_w[dir], oph, owTh);
        mfma_gemm<<<dim3(12, 6), 256, 0, stream>>>(
            oph + dir * D_MODEL, 2*D_MODEL, owTh, D_MODEL, D_INNER, D_MODEL,
            lengths, 0, 0, 4,
            nullptr, D_INNER, nullptr, nullptr, wdp, nullptr, nullptr, nullptr);
        // 6. big out-GEMM with RMS scale: fwd writes rbuf, bwd adds flipped
        if (dir == 0) {
            mfma_gemm<<<dim3(6, 64), 256, 0, stream>>>(
                yg_p, D_INNER, wdp, D_INNER, D_MODEL, D_INNER,
                lengths, 0, 0, 0,
                rbuf, D_MODEL, nullptr, nullptr, nullptr, op_b, x, sqs);
        } else {
            mfma_gemm<<<dim3(6, 64), 256, 0, stream>>>(
                yg_p, D_INNER, wdp, D_INNER, D_MODEL, D_INNER,
                lengths, 0, 1, 3,
                rbuf, D_MODEL, nullptr, nullptr, nullptr, nullptr, nullptr, sqs);
        }
    }

    // layernorm -> out
    layernorm_kernel<<<NROWS, 256, 0, stream>>>(rbuf, ln_g, ln_b, outp);
}

// Round 22
// 558.103 us; speedup vs baseline: 1.3980x; 1.0448x over previous
//
#include <hip/hip_runtime.h>
#include <cstdint>
#include <cstddef>

#define D_MODEL   768
#define D_STATE   64
#define D_INNER   1536
#define HEADDIM   64
#define NHEADS    24
#define D_CONV    4
#define CONV_DIM  1664      // D_INNER + 2*D_STATE
#define D_IN_PROJ 3224      // 2*D_INNER + 2*D_STATE + NHEADS
#define BATCH     4
#define SEQLEN    2048
#define NROWS     (BATCH*SEQLEN)   // 8192
#define NCHUNK    32
#define Q         64               // chunk length

typedef unsigned short u16;
typedef __attribute__((ext_vector_type(8))) short bf16x8;
typedef __attribute__((ext_vector_type(8))) unsigned short u16x8;
typedef __attribute__((ext_vector_type(4))) float f32x4;

__device__ __forceinline__ int flip_row(int m, const int* __restrict__ lengths) {
    int b = m >> 11;
    int t = m & (SEQLEN - 1);
    int len = lengths[b];
    int ft = (t < len) ? (len - 1 - t) : t;
    return (b << 11) | ft;
}

__device__ __forceinline__ u16 f2bf(float f) {
    unsigned int u = __float_as_uint(f);
    unsigned int r = u + 0x7FFFu + ((u >> 16) & 1u);
    return (u16)(r >> 16);
}
__device__ __forceinline__ float bf2f(u16 h) {
    return __uint_as_float(((unsigned int)h) << 16);
}

// f32 -> single bf16 array
__global__ __launch_bounds__(256)
void convert_single_kernel(const float* __restrict__ in, u16* __restrict__ hi, int n4)
{
    int i = blockIdx.x * 256 + threadIdx.x;
    if (i >= n4) return;
    float4 v = *(const float4*)(in + (size_t)i * 4);
    ushort4 h;
    h.x = f2bf(v.x); h.y = f2bf(v.y); h.z = f2bf(v.z); h.w = f2bf(v.w);
    *(ushort4*)(hi + (size_t)i * 4) = h;
}

// prep for fused output projection: (a) op_w (768x1536) -> single bf16,
// (b) transpose out_w (768x1536) -> owT[1536][768] single bf16
#define NCONV_BLK 1152    // 768*1536/4/256
#define NT_BLK    288     // 24 x 12 transpose tiles
__global__ __launch_bounds__(256)
void prep_outw_kernel(const float* __restrict__ op_w, const float* __restrict__ ow,
                      u16* __restrict__ oph, u16* __restrict__ owTh)
{
    const int bid = blockIdx.x;
    const int tid = threadIdx.x;
    if (bid < NCONV_BLK) {
        int i = bid * 256 + tid;
        float4 v = *(const float4*)(op_w + (size_t)i * 4);
        ushort4 h;
        h.x = f2bf(v.x); h.y = f2bf(v.y); h.z = f2bf(v.z); h.w = f2bf(v.w);
        *(ushort4*)(oph + (size_t)i * 4) = h;
        return;
    }
    __shared__ float T[64][65];
    const int tb = bid - NCONV_BLK;
    const int e0 = (tb % 24) * 64;
    const int d0 = (tb / 24) * 64;
    const int col = tid & 63, rg = tid >> 6;
    #pragma unroll
    for (int i = 0; i < 16; i++) {
        int r = rg + i * 4;
        T[r][col] = ow[(size_t)(d0 + r) * D_INNER + e0 + col];
    }
    __syncthreads();
    const int er = tid >> 2, dc0 = (tid & 3) * 16;
    u16x8 ph[2];
    #pragma unroll
    for (int j = 0; j < 16; j++)
        ph[j >> 3][j & 7] = f2bf(T[dc0 + j][er]);
    size_t obase = (size_t)(e0 + er) * D_MODEL + d0 + dc0;
    *(u16x8*)(owTh + obase)     = ph[0];
    *(u16x8*)(owTh + obase + 8) = ph[1];
}

// ---------- single-bf16 MFMA GEMM, BK=32, DOUBLE-BUFFERED LDS ----------
// 128x128 tile, 256 threads = 4 waves (2x2), 4x4 16x16 frags/wave.
// mode 0: C f32 = scale*acc + bias[n] + resid[m]       (scale from sqsum)
// mode 1: split store BF16 -> Cz16 | Cxbc16 (dt columns handled by dt_exact)
// mode 3: C[crow*ldc+n] += scale*acc (sequential launches only)
// mode 4: Cp[crow*ldc+n] = bf16(acc)
__global__ __launch_bounds__(256, 4)
void mfma_gemm(const u16* __restrict__ A, int lda,
               const u16* __restrict__ W, int ldw,
               int N, int K, const int* __restrict__ lengths,
               int flipA, int flipC, int mode,
               float* __restrict__ C, int ldc,
               u16* __restrict__ Cz16, u16* __restrict__ Cxbc16,
               u16* __restrict__ Cp,
               const float* __restrict__ bias, const float* __restrict__ resid,
               const float* __restrict__ sqsum)
{
    __shared__ alignas(16) u16 lds[2 * 2 * 4096];   // [buf][matrix][4096]
    const int tid = threadIdx.x;
    const int m0 = blockIdx.y * 128;
    const int n0 = blockIdx.x * 128;
    const int lane = tid & 63;
    const int wid = tid >> 6;
    const int wm = wid >> 1, wn = wid & 1;

    const int kh = tid & 3;           // k-group (8 u16 each), 0..3
    const int rb = tid >> 2;          // 0..63
    int aoff[2], woff[2], lws[2];
    #pragma unroll
    for (int c = 0; c < 2; c++) {
        int row = rb + c * 64;
        int grow = m0 + row;
        if (flipA) grow = flip_row(grow, lengths);
        aoff[c] = grow * lda + kh * 8;
        int wrow = n0 + row; if (wrow >= N) wrow = N - 1;
        woff[c] = wrow * ldw + kh * 8;
        lws[c] = kh * 1024 + ((row & 0x78) | ((row ^ (kh << 1)) & 7)) * 8;
    }

    f32x4 acc[4][4];
    const f32x4 zero4 = {0.f, 0.f, 0.f, 0.f};
    #pragma unroll
    for (int i = 0; i < 4; i++)
        #pragma unroll
        for (int j = 0; j < 4; j++) acc[i][j] = zero4;

    const int l15 = lane & 15, lq = lane >> 4;
    const int arow0 = wm * 64 + l15;
    const int wrow0 = wn * 64 + l15;
    const int abase = lq * 1024 + ((arow0 & 0x78) | ((arow0 ^ (lq << 1)) & 7)) * 8;
    const int wbase = lq * 1024 + ((wrow0 & 0x78) | ((wrow0 ^ (lq << 1)) & 7)) * 8;

    // prologue: tile 0 -> buf0 ; prefetch tile 1 into regs
    u16x8 va[2], vc[2];
    #pragma unroll
    for (int c = 0; c < 2; c++) {
        va[c] = *(const u16x8*)(A + (size_t)aoff[c]);
        vc[c] = *(const u16x8*)(W + (size_t)woff[c]);
    }
    #pragma unroll
    for (int c = 0; c < 2; c++) {
        *(u16x8*)(lds + 0 * 4096 + lws[c]) = va[c];
        *(u16x8*)(lds + 1 * 4096 + lws[c]) = vc[c];
    }
    if (K > 32) {
        #pragma unroll
        for (int c = 0; c < 2; c++) {
            va[c] = *(const u16x8*)(A + (size_t)aoff[c] + 32);
            vc[c] = *(const u16x8*)(W + (size_t)woff[c] + 32);
        }
    }
    __syncthreads();

    int cur = 0;
    for (int kt = 0; kt < K; kt += 32) {
        u16* Lc = lds + cur * 8192;
        if (kt + 32 < K) {
            u16* Ln = lds + (cur ^ 1) * 8192;
            #pragma unroll
            for (int c = 0; c < 2; c++) {           // stage tile k+1 -> other buf
                *(u16x8*)(Ln + 0 * 4096 + lws[c]) = va[c];
                *(u16x8*)(Ln + 1 * 4096 + lws[c]) = vc[c];
            }
            if (kt + 64 < K) {                      // prefetch tile k+2
                #pragma unroll
                for (int c = 0; c < 2; c++) {
                    va[c] = *(const u16x8*)(A + (size_t)aoff[c] + kt + 64);
                    vc[c] = *(const u16x8*)(W + (size_t)woff[c] + kt + 64);
                }
            }
        }
        bf16x8 ah[4], wv[4];
        #pragma unroll
        for (int f = 0; f < 4; f++) {
            ah[f] = *(const bf16x8*)(Lc + 0 * 4096 + abase + f * 128);
            wv[f] = *(const bf16x8*)(Lc + 1 * 4096 + wbase + f * 128);
        }
        #pragma unroll
        for (int fr = 0; fr < 4; fr++)
            #pragma unroll
            for (int fc = 0; fc < 4; fc++)
                acc[fr][fc] = __builtin_amdgcn_mfma_f32_16x16x32_bf16(
                    ah[fr], wv[fc], acc[fr][fc], 0, 0, 0);
        __syncthreads();                            // single barrier per K-step
        cur ^= 1;
    }

    #pragma unroll
    for (int fr = 0; fr < 4; fr++) {
        int mr[4], crow[4];
        float scl[4];
        #pragma unroll
        for (int r = 0; r < 4; r++) {
            mr[r] = m0 + wm * 64 + fr * 16 + lq * 4 + r;
            crow[r] = flipC ? flip_row(mr[r], lengths) : mr[r];
            scl[r] = sqsum ? rsqrtf(sqsum[mr[r]] * (1.f / D_INNER) + 1e-5f) : 1.f;
        }
        #pragma unroll
        for (int fc = 0; fc < 4; fc++) {
            const int nb = n0 + wn * 64 + fc * 16;
            const int nn = nb + l15;
            if (nn >= N) continue;
            #pragma unroll
            for (int r = 0; r < 4; r++) {
                float v = acc[fr][fc][r];
                if (mode == 1) {
                    if (nb < D_INNER)
                        Cz16[(size_t)crow[r] * D_INNER + nn] = f2bf(v);
                    else if (nb < D_INNER + CONV_DIM)
                        Cxbc16[(size_t)crow[r] * CONV_DIM + (nn - D_INNER)] = f2bf(v);
                    // dt columns handled exactly by dt_exact_kernel
                } else if (mode == 3) {
                    C[(size_t)crow[r] * ldc + nn] += v * scl[r];
                } else if (mode == 4) {
                    Cp[(size_t)crow[r] * ldc + nn] = f2bf(v);
                } else {
                    v = v * scl[r] + bias[nn] + resid[(size_t)mr[r] * D_MODEL + nn];
                    C[(size_t)crow[r] * ldc + nn] = v;
                }
            }
        }
    }
}

// exact fp32 dt_raw: la[row][h] = dot(x[fliprow], in_w[3200+h])  (24 heads)
// also zeroes sqsum[row] (removes a separate memset launch)
__global__ __launch_bounds__(256)
void dt_exact_kernel(const float* __restrict__ x, const float* __restrict__ wdt,
                     const int* __restrict__ lengths, int flipA,
                     float* __restrict__ la, float* __restrict__ sqsum)
{
    const int wv = threadIdx.x >> 6, lane = threadIdx.x & 63;
    const int row = blockIdx.x * 4 + wv;
    int grow = flipA ? flip_row(row, lengths) : row;
    const float* xr = x + (size_t)grow * D_MODEL;
    float xv[12];
    #pragma unroll
    for (int k = 0; k < 12; k++) xv[k] = xr[k * 64 + lane];
    if (lane == 1) sqsum[row] = 0.f;
    for (int c = 0; c < NHEADS; c++) {
        const float* wr = wdt + (size_t)c * D_MODEL;
        float acc = 0.f;
        #pragma unroll
        for (int k = 0; k < 12; k++) acc = fmaf(xv[k], wr[k * 64 + lane], acc);
        #pragma unroll
        for (int o = 32; o > 0; o >>= 1) acc += __shfl_xor(acc, o);
        if (lane == 0) la[(size_t)row * NHEADS + c] = acc;
    }
}

// fused causal conv + silu + per-chunk transpose + (cg==26) dt/cumsum
// xbcr is bf16; outputs: xT single [tile][p][s], bc single [row][128]
__global__ __launch_bounds__(256)
void conv_silu_fused_kernel(const u16* __restrict__ xbcr, const float* __restrict__ cw,
                            const float* __restrict__ cb,
                            u16* __restrict__ xT, u16* __restrict__ bc,
                            const float* __restrict__ dt_bias, const float* __restrict__ A_log,
                            float* __restrict__ dtb, float* __restrict__ la)
{
    __shared__ float T[64][65];
    const int cg = blockIdx.x;
    const int rc = blockIdx.y;
    const int tid = threadIdx.x;
    if (cg == 26) {
        const int lane2 = tid & 63, w = tid >> 6;
        const int row0 = rc * 64;
        #pragma unroll
        for (int i = 0; i < 6; i++) {
            int h = w * 6 + i;
            size_t idx = (size_t)(row0 + lane2) * NHEADS + h;
            float v = la[idx] + dt_bias[h];
            float sp = (v > 20.f) ? v : log1pf(expf(v));
            dtb[idx] = sp;
            float dA = sp * (-expf(A_log[h]));
            #pragma unroll
            for (int o = 1; o < 64; o <<= 1) {
                float u = __shfl_up(dA, o);
                if (lane2 >= o) dA += u;
            }
            la[idx] = dA;
        }
        return;
    }
    const int col = tid & 63, rg = tid >> 6;
    const int c = cg * 64 + col;
    const int rstart = rc * 64 + rg * 16;
    const int t0 = rstart & (SEQLEN - 1);
    const float c0 = cw[c*4+0], c1 = cw[c*4+1], c2 = cw[c*4+2], c3 = cw[c*4+3];
    const float cbv = cb[c];
    const u16* base = xbcr + (size_t)rstart * CONV_DIM + c;
    float w0 = (t0 >= 3) ? bf2f(base[-3 * CONV_DIM]) : 0.f;
    float w1 = (t0 >= 2) ? bf2f(base[-2 * CONV_DIM]) : 0.f;
    float w2 = (t0 >= 1) ? bf2f(base[-1 * CONV_DIM]) : 0.f;
    const bool isx = (cg < 24);
    #pragma unroll
    for (int r = 0; r < 16; r++) {
        float w3 = bf2f(base[r * CONV_DIM]);
        float acc = cbv + w0*c0 + w1*c1 + w2*c2 + w3*c3;
        float val = acc / (1.f + expf(-acc));
        if (isx) {
            T[rg*16 + r][col] = val;
        } else {
            bc[(size_t)(rstart + r) * 128 + (c - D_INNER)] = f2bf(val);
        }
        w0 = w1; w1 = w2; w2 = w3;
    }
    if (!isx) return;
    __syncthreads();
    const int p = tid >> 2, s0 = (tid & 3) * 16;
    size_t tile = (size_t)(((rc >> 5) * NHEADS + cg) * NCHUNK + (rc & 31));
    size_t obase = tile * 4096 + p * 64 + s0;
    u16x8 ph[2];
    #pragma unroll
    for (int j = 0; j < 16; j++)
        ph[j >> 3][j & 7] = f2bf(T[s0 + j][p]);
    *(u16x8*)(xT + obase)     = ph[0];
    *(u16x8*)(xT + obase + 8) = ph[1];
}

// single-bf16 64x64x64 GEMM helper: 1 MFMA per fragment.
__device__ __forceinline__ void gemm1(const u16* rA, const u16* rW,
                                      int ar0, int wr0, int lq, f32x4 acc[2][2])
{
    #pragma unroll
    for (int kk = 0; kk < 2; kk++) {
        const int khs = kk * 4 + lq;
        const int ab = khs * 512 + ((ar0 & 0x38) | ((ar0 ^ khs) & 7)) * 8;
        const int wb = khs * 512 + ((wr0 & 0x38) | ((wr0 ^ khs) & 7)) * 8;
        bf16x8 ah[2], wh[2];
        #pragma unroll
        for (int f = 0; f < 2; f++) {
            ah[f] = *(const bf16x8*)(rA + ab + f * 128);
            wh[f] = *(const bf16x8*)(rW + wb + f * 128);
        }
        #pragma unroll
        for (int fr = 0; fr < 2; fr++)
            #pragma unroll
            for (int fc = 0; fc < 2; fc++)
                acc[fr][fc] = __builtin_amdgcn_mfma_f32_16x16x32_bf16(
                    ah[fr], wh[fc], acc[fr][fc], 0, 0, 0);
    }
}

// chunk state: S(p,n) = sum_s exp(la63-la[s]) dt[s] x[s][p] B[s][n]  -> hloc bf16
__global__ __launch_bounds__(256)
void chunk_state_kernel(const u16* __restrict__ xT, const u16* __restrict__ bc,
                        const float* __restrict__ la, const float* __restrict__ dtb,
                        u16* __restrict__ hloc)
{
    __shared__ alignas(16) u16 lA[4096];
    __shared__ alignas(16) u16 lW[4096];
    __shared__ float la_sh[64], w_sh[64];
    const int bh = blockIdx.x, c = blockIdx.y;
    const int b = bh / NHEADS, h = bh - b * NHEADS;
    const int row0 = b * SEQLEN + c * Q;
    const size_t tile = (size_t)(bh * NCHUNK + c);
    const int tid = threadIdx.x;

    if (tid < 64) la_sh[tid] = la[(size_t)(row0 + tid) * NHEADS + h];
    __syncthreads();
    if (tid < 64)
        w_sh[tid] = expf(la_sh[63] - la_sh[tid]) * dtb[(size_t)(row0 + tid) * NHEADS + h];
    {
        const int kh = tid & 7, rr = tid >> 3;
        #pragma unroll
        for (int cc = 0; cc < 2; cc++) {
            int row = rr + cc * 32;
            int lws = kh * 512 + ((row & 0x38) | ((row ^ kh) & 7)) * 8;
            *(u16x8*)(lA + lws) = *(const u16x8*)(xT + tile * 4096 + row * 64 + kh * 8);
        }
    }
    __syncthreads();
    {
        const int n = tid & 63, sg = tid >> 6;
        #pragma unroll
        for (int i = 0; i < 16; i++) {
            int s = sg + i * 4;
            float bv = bf2f(bc[(size_t)(row0 + s) * 128 + n]);
            float v = bv * w_sh[s];
            int addr = (s >> 3) * 512 + ((n & 0x38) | ((n ^ (s >> 3)) & 7)) * 8 + (s & 7);
            lW[addr] = f2bf(v);
        }
    }
    __syncthreads();
    const int lane = tid & 63, wid = tid >> 6;
    const int wm = wid >> 1, wn = wid & 1;
    const int l15 = lane & 15, lq = lane >> 4;
    f32x4 acc[2][2];
    const f32x4 z4 = {0.f, 0.f, 0.f, 0.f};
    acc[0][0] = z4; acc[0][1] = z4; acc[1][0] = z4; acc[1][1] = z4;
    gemm1(lA, lW, wm * 32 + l15, wn * 32 + l15, lq, acc);
    #pragma unroll
    for (int fr = 0; fr < 2; fr++)
        #pragma unroll
        for (int fc = 0; fc < 2; fc++)
            #pragma unroll
            for (int r = 0; r < 4; r++) {
                int p = wm * 32 + fr * 16 + lq * 4 + r;
                int n = wn * 32 + fc * 16 + l15;
                hloc[tile * 4096 + p * 64 + n] = f2bf(acc[fr][fc][r]);
            }
}

// in-place sequential fold over bf16 states: hloc[c] := state ENTERING chunk c
// grid (96 bh, 16 p-slices) x 256 threads; running accumulation in f32 regs
__global__ __launch_bounds__(256)
void combine_kernel(u16* __restrict__ hloc, const float* __restrict__ la)
{
    const int bh = blockIdx.x;
    const int b = bh / NHEADS, h = bh - b * NHEADS;
    const int off = blockIdx.y * 256 + threadIdx.x;
    float run = 0.f;
    for (int c = 0; c < NCHUNK; c++) {
        u16* ptr = hloc + ((size_t)(bh * NCHUNK + c)) * 4096 + off;
        float sv = bf2f(*ptr);
        *ptr = f2bf(run);
        float cd = expf(la[(size_t)(b * SEQLEN + c * Q + Q - 1) * NHEADS + h]);
        run = fmaf(run, cd, sv);
    }
}

// chunk y + fused gate/norm_w/sqsum, all single-bf16 gemms; z, hloc bf16
__global__ __launch_bounds__(256)
void chunk_y_kernel(const u16* __restrict__ xT, const u16* __restrict__ bc,
                    const u16* __restrict__ hloc, const float* __restrict__ la,
                    const float* __restrict__ dtb, const float* __restrict__ Dp,
                    const u16* __restrict__ z16, const float* __restrict__ norm_w,
                    u16* __restrict__ ygp, float* __restrict__ sqsum)
{
    __shared__ alignas(16) u16 r1[4096];   // C -> P (single)
    __shared__ alignas(16) u16 r2[4096];   // hin -> B -> x (single)
    __shared__ float la_sh[64], dt_sh[64], ssh[64];
    const int bh = blockIdx.x, c = blockIdx.y;
    const int b = bh / NHEADS, h = bh - b * NHEADS;
    const int row0 = b * SEQLEN + c * Q;
    const size_t tile = (size_t)(bh * NCHUNK + c);
    const int tid = threadIdx.x;
    if (tid < 64) {
        la_sh[tid] = la[(size_t)(row0 + tid) * NHEADS + h];
        dt_sh[tid] = dtb[(size_t)(row0 + tid) * NHEADS + h];
        ssh[tid] = 0.f;
    }
    const int kh = tid & 7, rr = tid >> 3;
    #pragma unroll
    for (int cc = 0; cc < 2; cc++) {
        int row = rr + cc * 32;
        int lws = kh * 512 + ((row & 0x38) | ((row ^ kh) & 7)) * 8;
        *(u16x8*)(r1 + lws) = *(const u16x8*)(bc + (size_t)(row0 + row) * 128 + 64 + kh * 8);
        *(u16x8*)(r2 + lws) = *(const u16x8*)(hloc + tile * 4096 + row * 64 + kh * 8);
    }
    __syncthreads();
    const int lane = tid & 63, wid = tid >> 6;
    const int wm = wid >> 1, wn = wid & 1;
    const int l15 = lane & 15, lq = lane >> 4;
    const int ar0 = wm * 32 + l15, wr0 = wn * 32 + l15;
    const f32x4 z4 = {0.f, 0.f, 0.f, 0.f};
    f32x4 acc2[2][2];
    acc2[0][0] = z4; acc2[0][1] = z4; acc2[1][0] = z4; acc2[1][1] = z4;
    gemm1(r1, r2, ar0, wr0, lq, acc2);
    __syncthreads();
    #pragma unroll
    for (int cc = 0; cc < 2; cc++) {
        int row = rr + cc * 32;
        int lws = kh * 512 + ((row & 0x38) | ((row ^ kh) & 7)) * 8;
        *(u16x8*)(r2 + lws) = *(const u16x8*)(bc + (size_t)(row0 + row) * 128 + kh * 8);
    }
    __syncthreads();
    f32x4 accG[2][2];
    accG[0][0] = z4; accG[0][1] = z4; accG[1][0] = z4; accG[1][1] = z4;
    gemm1(r1, r2, ar0, wr0, lq, accG);
    __syncthreads();
    const float Dph = Dp[h];
    #pragma unroll
    for (int fr = 0; fr < 2; fr++)
        #pragma unroll
        for (int fc = 0; fc < 2; fc++)
            #pragma unroll
            for (int r = 0; r < 4; r++) {
                int t = wm * 32 + fr * 16 + lq * 4 + r;
                int s = wn * 32 + fc * 16 + l15;
                float v = 0.f;
                if (s <= t) v = accG[fr][fc][r] * expf(la_sh[t] - la_sh[s]) * dt_sh[s];
                if (s == t) v += Dph;
                int addr = (s >> 3) * 512 + ((t & 0x38) | ((t ^ (s >> 3)) & 7)) * 8 + (s & 7);
                r1[addr] = f2bf(v);
            }
    #pragma unroll
    for (int cc = 0; cc < 2; cc++) {
        int row = rr + cc * 32;
        int lws = kh * 512 + ((row & 0x38) | ((row ^ kh) & 7)) * 8;
        *(u16x8*)(r2 + lws) = *(const u16x8*)(xT + tile * 4096 + row * 64 + kh * 8);
    }
    __syncthreads();
    f32x4 acc1[2][2];
    acc1[0][0] = z4; acc1[0][1] = z4; acc1[1][0] = z4; acc1[1][1] = z4;
    gemm1(r1, r2, ar0, wr0, lq, acc1);
    // fused epilogue: gate + norm_w + single-bf16 store + sqsum
    #pragma unroll
    for (int fr = 0; fr < 2; fr++)
        #pragma unroll
        for (int r = 0; r < 4; r++) {
            int t = wm * 32 + fr * 16 + lq * 4 + r;
            size_t row = row0 + t;
            float Et = expf(la_sh[t]);
            float s2 = 0.f;
            #pragma unroll
            for (int fc = 0; fc < 2; fc++) {
                int hp = h * 64 + wn * 32 + fc * 16 + l15;
                float yv = acc1[fr][fc][r] + Et * acc2[fr][fc][r];
                float zv = bf2f(z16[row * D_INNER + hp]);
                float gv = yv * (zv / (1.f + expf(-zv)));
                s2 = fmaf(gv, gv, s2);
                float gn = gv * norm_w[hp];
                ygp[row * D_INNER + hp] = f2bf(gn);
            }
            s2 += __shfl_xor(s2, 1);
            s2 += __shfl_xor(s2, 2);
            s2 += __shfl_xor(s2, 4);
            s2 += __shfl_xor(s2, 8);
            if (l15 == 0) atomicAdd(&ssh[t], s2);
        }
    __syncthreads();
    if (tid < 64) atomicAdd(&sqsum[row0 + tid], ssh[tid]);
}

__global__ __launch_bounds__(256)
void layernorm_kernel(const float* __restrict__ r, const float* __restrict__ gam,
                      const float* __restrict__ bet, float* __restrict__ out)
{
    const int row = blockIdx.x;
    const float* rr = r + (size_t)row * D_MODEL;
    const int tid = threadIdx.x;
    float v[3];
    float s = 0.f, s2 = 0.f;
    #pragma unroll
    for (int i = 0; i < 3; i++) {
        v[i] = rr[tid + i * 256];
        s += v[i];
        s2 = fmaf(v[i], v[i], s2);
    }
    #pragma unroll
    for (int o = 32; o > 0; o >>= 1) { s += __shfl_xor(s, o); s2 += __shfl_xor(s2, o); }
    __shared__ float rs[4], rs2[4];
    if ((tid & 63) == 0) { rs[tid >> 6] = s; rs2[tid >> 6] = s2; }
    __syncthreads();
    float S  = rs[0] + rs[1] + rs[2] + rs[3];
    float S2 = rs2[0] + rs2[1] + rs2[2] + rs2[3];
    float mu  = S * (1.f / D_MODEL);
    float var = S2 * (1.f / D_MODEL) - mu * mu;
    float inv = rsqrtf(var + 1e-5f);
    #pragma unroll
    for (int i = 0; i < 3; i++) {
        int e = tid + i * 256;
        out[(size_t)row * D_MODEL + e] = (v[i] - mu) * inv * gam[e] + bet[e];
    }
}

extern "C" void kernel_launch(void* const* d_in, const int* in_sizes, int n_in,
                              void* d_out, int out_size, void* d_ws, size_t ws_size,
                              hipStream_t stream)
{
    const float* x        = (const float*)d_in[0];
    const int*   lengths  = (const int*)d_in[1];
    const float* in_w[2]    = {(const float*)d_in[2],  (const float*)d_in[10]};
    const float* conv_w[2]  = {(const float*)d_in[3],  (const float*)d_in[11]};
    const float* conv_b[2]  = {(const float*)d_in[4],  (const float*)d_in[12]};
    const float* dt_bias[2] = {(const float*)d_in[5],  (const float*)d_in[13]};
    const float* A_log[2]   = {(const float*)d_in[6],  (const float*)d_in[14]};
    const float* Dp[2]      = {(const float*)d_in[7],  (const float*)d_in[15]};
    const float* norm_w[2]  = {(const float*)d_in[8],  (const float*)d_in[16]};
    const float* out_w[2]   = {(const float*)d_in[9],  (const float*)d_in[17]};
    const float* op_w = (const float*)d_in[18];
    const float* op_b = (const float*)d_in[19];
    const float* ln_g = (const float*)d_in[20];
    const float* ln_b = (const float*)d_in[21];
    float* outp = (float*)d_out;

    // ---- workspace layout (bf16 interchange; hloc bf16 DEDICATED) ----
    u16*  z16   = (u16*)d_ws;                                 // 8192*1536 u16
    u16*  xbcr16= z16 + (size_t)NROWS * D_INNER;              // 8192*1664 u16
    float* la   = (float*)(xbcr16 + (size_t)NROWS * CONV_DIM);
    float* dtb  = la  + (size_t)NROWS * NHEADS;
    float* sqs  = dtb + (size_t)NROWS * NHEADS;               // 8192 f32
    u16*  xT    = (u16*)(sqs + NROWS);                        // 8192*1536 u16
    u16*  bc    = xT + (size_t)NROWS * D_INNER;               // 8192*128 u16
    u16*  R4    = bc + (size_t)NROWS * 128;                   // iw / yg_p (8192*1536 u16)
    u16*  R5    = R4 + (size_t)NROWS * D_INNER;               // xq + rbuf
    u16*  xq    = R5;                                         // 8192*768 u16
    float* rbuf = (float*)(R5 + (size_t)NROWS * D_MODEL);     // 8192*768 f32
    u16*  hloc  = (u16*)(rbuf + (size_t)NROWS * D_MODEL);     // 96*32*4096 u16 (DEDICATED)

    u16*  iw   = R4;                  // in_w single bf16 (dead before chunk_y)
    u16*  yg_p = R4;                  // gated-y single bf16 (rows of 1536)

    // per-dir out-proj prep overlays xT (dead after chunk_y)
    u16* oph  = xT;
    u16* owTh = oph  + (size_t)D_MODEL * D_INNER;
    u16* wdp  = owTh + (size_t)D_MODEL * D_INNER;   // 768 x 1536 single bf16

    size_t need = ((size_t)(hloc + (size_t)BATCH*NHEADS*NCHUNK*4096) - (size_t)d_ws);
    if (ws_size < need) return;

    // x single bf16 once (flip handled by GEMM row indexing)
    convert_single_kernel<<<(NROWS*D_MODEL/4 + 255)/256, 256, 0, stream>>>(
        x, xq, NROWS*D_MODEL/4);

    for (int dir = 0; dir < 2; dir++) {
        // 0. convert in_w single bf16 (R4)
        convert_single_kernel<<<(D_IN_PROJ*D_MODEL/4 + 255)/256, 256, 0, stream>>>(
            in_w[dir], iw, D_IN_PROJ*D_MODEL/4);
        // 1. in_proj (split bf16 outputs): [z16 | xbcr16], dt cols skipped
        mfma_gemm<<<dim3(26, 64), 256, 0, stream>>>(
            xq, D_MODEL, iw, D_MODEL, D_IN_PROJ, D_MODEL,
            lengths, dir, 0, 1,
            nullptr, 0, z16, xbcr16, nullptr, nullptr, nullptr, nullptr);
        // 1b. exact fp32 dt_raw -> la ; zero sqs
        dt_exact_kernel<<<NROWS/4, 256, 0, stream>>>(
            x, in_w[dir] + (size_t)(D_INNER + CONV_DIM) * D_MODEL, lengths, dir, la, sqs);
        // 2. conv + silu + transpose + dt/cumsum (bf16 in, bf16 out)
        conv_silu_fused_kernel<<<dim3(27, BATCH*NCHUNK), 256, 0, stream>>>(
            xbcr16, conv_w[dir], conv_b[dir], xT, bc,
            dt_bias[dir], A_log[dir], dtb, la);
        // 3. chunked SSD scan (single-bf16 gemms, bf16 states)
        chunk_state_kernel<<<dim3(BATCH*NHEADS, NCHUNK), 256, 0, stream>>>(
            xT, bc, la, dtb, hloc);
        combine_kernel<<<dim3(BATCH*NHEADS, 16), 256, 0, stream>>>(hloc, la);
        // 4. chunk_y with fused gate + norm_w + sqsum (single bf16 -> yg_p)
        chunk_y_kernel<<<dim3(BATCH*NHEADS, NCHUNK), 256, 0, stream>>>(
            xT, bc, hloc, la, dtb, Dp[dir], z16, norm_w[dir], yg_p, sqs);
        // 5. fused output projection: Wd = op_w[:, dir*768:+768] @ out_w
        prep_outw_kernel<<<NCONV_BLK + NT_BLK, 256, 0, stream>>>(
            op_w, out_w[dir], oph, owTh);
        mfma_gemm<<<dim3(12, 6), 256, 0, stream>>>(
            oph + dir * D_MODEL, 2*D_MODEL, owTh, D_MODEL, D_INNER, D_MODEL,
            lengths, 0, 0, 4,
            nullptr, D_INNER, nullptr, nullptr, wdp, nullptr, nullptr, nullptr);
        // 6. big out-GEMM with RMS scale: fwd writes rbuf, bwd adds flipped
        if (dir == 0) {
            mfma_gemm<<<dim3(6, 64), 256, 0, stream>>>(
                yg_p, D_INNER, wdp, D_INNER, D_MODEL, D_INNER,
                lengths, 0, 0, 0,
                rbuf, D_MODEL, nullptr, nullptr, nullptr, op_b, x, sqs);
        } else {
            mfma_gemm<<<dim3(6, 64), 256, 0, stream>>>(
                yg_p, D_INNER, wdp, D_INNER, D_MODEL, D_INNER,
                lengths, 0, 1, 3,
                rbuf, D_MODEL, nullptr, nullptr, nullptr, nullptr, nullptr, sqs);
        }
    }

    // layernorm -> out
    layernorm_kernel<<<NROWS, 256, 0, stream>>>(rbuf, ln_g, ln_b, outp);
}